// Round 5
// baseline (891.551 us; speedup 1.0000x reference)
//
#include <hip/hip_runtime.h>

#define TPB 256

typedef __attribute__((ext_vector_type(8))) short s8v;
typedef __attribute__((ext_vector_type(4))) float f4v;
typedef __bf16 bf16x8v __attribute__((ext_vector_type(8)));

__device__ inline short f2b(float f) {
    unsigned u = __builtin_bit_cast(unsigned, f);
    unsigned r = (u + 0x7FFF + ((u >> 16) & 1)) >> 16;
    return (short)r;
}
__device__ inline float b2f(short s) {
    unsigned u = ((unsigned)(unsigned short)s) << 16;
    return __builtin_bit_cast(float, u);
}
__device__ inline f4v mfma16(s8v a, s8v b, f4v c) {
    return __builtin_amdgcn_mfma_f32_16x16x32_bf16(
        __builtin_bit_cast(bf16x8v, a), __builtin_bit_cast(bf16x8v, b), c, 0, 0, 0);
}

// ---------------------------------------------------------------------------
// Fused weight transpose: OIHW (or IOHW) fp32 -> [tap][co][ci] bf16
// ---------------------------------------------------------------------------
struct WtDesc { const float* src; int CO, CI, T, iohw, start; };
struct WtArgs { WtDesc d[13]; int total; };

__global__ __launch_bounds__(256)
void wtall_k(WtArgs a, short* dst)
{
    int i = blockIdx.x * 256 + threadIdx.x;
    if (i >= a.total) return;
    int s = 0;
    for (int j = 1; j < 13; ++j) if (i >= a.d[j].start) s = j;
    int off = i - a.d[s].start;
    int CI = a.d[s].CI, CO = a.d[s].CO, T = a.d[s].T;
    int ci = off % CI; int rest = off / CI; int co = rest % CO; int tap = rest / CO;
    float v = a.d[s].iohw ? a.d[s].src[(ci * CO + co) * T + tap]
                          : a.d[s].src[(co * CI + ci) * T + tap];
    dst[i] = f2b(v);
}

// Codebook split: cb fp32 [512][64] -> hi bf16, lo bf16, |c|^2 fp32
__global__ __launch_bounds__(256)
void cbprep_k(const float* __restrict__ cb, short* __restrict__ cbh,
              short* __restrict__ cbl, float* __restrict__ cbsq)
{
    int c = blockIdx.x * 256 + threadIdx.x;   // 0..511
    const float* src = cb + (size_t)c * 64;
    float sq = 0.f;
#pragma unroll
    for (int g = 0; g < 8; ++g) {
        s8v hi, lo;
#pragma unroll
        for (int j = 0; j < 8; ++j) {
            float v = src[g * 8 + j];
            sq += v * v;
            short h = f2b(v);
            hi[j] = h;
            lo[j] = f2b(v - b2f(h));
        }
        *(s8v*)(cbh + (size_t)c * 64 + g * 8) = hi;
        *(s8v*)(cbl + (size_t)c * 64 + g * 8) = lo;
    }
    cbsq[c] = sq;
}

// ---------------------------------------------------------------------------
// conv1: x (16,1,256,256) fp32 -> h1 NHWC bf16 (16,128,128,64), k4 s2 p1.
// ---------------------------------------------------------------------------
__global__ __launch_bounds__(256)
void conv1_k(const float* __restrict__ x, const float* __restrict__ w,
             const float* __restrict__ bias, short* __restrict__ out)
{
    __shared__ float sx[4 * 256];
    const int tid = threadIdx.x;
    const int oh = blockIdx.x, n = blockIdx.y;
    const int co = tid & 63, wv = tid >> 6;

    float wr[16];
#pragma unroll
    for (int t = 0; t < 16; ++t) wr[t] = w[co * 16 + t];
    const float b = bias[co];

    const float* xp = x + (size_t)n * 65536;
    for (int e = tid; e < 1024; e += 256) {
        int kh = e >> 8, col = e & 255;
        int ih = oh * 2 - 1 + kh;
        sx[e] = ((unsigned)ih < 256u) ? xp[ih * 256 + col] : 0.f;
    }
    __syncthreads();

    short* op = out + (((size_t)n * 128 + oh) * 128) * 64 + co;
#pragma unroll 4
    for (int i = 0; i < 32; ++i) {
        int ow = wv * 32 + i;
        int iwb = ow * 2 - 1;
        float acc = b;
#pragma unroll
        for (int kh = 0; kh < 4; ++kh) {
#pragma unroll
            for (int kw = 0; kw < 4; ++kw) {
                int iw = iwb + kw;
                float v = ((unsigned)iw < 256u) ? sx[kh * 256 + iw] : 0.f;
                acc = fmaf(v, wr[kh * 4 + kw], acc);
            }
        }
        op[(size_t)ow * 64] = f2b(fmaxf(acc, 0.f));
    }
}

// ---------------------------------------------------------------------------
// Generic MFMA implicit-GEMM conv (per-tap staging) — used for k4s2 & 1x1.
// ---------------------------------------------------------------------------
template<int KH, int KW, int S, int P, int CI, int CO,
         bool RELU_IN, bool RELU_OUT, bool RES, bool OUT_F32>
__global__ __launch_bounds__(256)
void mconv_k(const short* __restrict__ in, const short* __restrict__ wt,
             const float* __restrict__ bias, const short* __restrict__ res,
             void* __restrict__ outv)
{
    constexpr int NT = CO / 16;
    constexpr int KC = CI / 32;
    constexpr int T  = KH * KW;
    constexpr int H  = 64 * S, W = 64 * S;
    __shared__ short sA[128 * 40];
    __shared__ short sB[CO * 40];

    const int tid = threadIdx.x;
    const int oh0 = blockIdx.x * 2;
    const int n   = blockIdx.y;
    const short* inb = in + (size_t)n * H * W * CI;
    const int w = tid >> 6, l = tid & 63, rl = l & 15, qd = l >> 4;

    f4v acc0[NT], acc1[NT];
#pragma unroll
    for (int nt = 0; nt < NT; ++nt) { acc0[nt] = (f4v)0.f; acc1[nt] = (f4v)0.f; }

    for (int tap = 0; tap < T; ++tap) {
        const int kh = tap / KW, kw = tap % KW;
        const short* wp = wt + (size_t)tap * CO * CI;
        for (int kc = 0; kc < KC; ++kc) {
            __syncthreads();
#pragma unroll
            for (int e = tid; e < 512; e += 256) {
                int row = e >> 2, kcn = e & 3;
                int ohl = row >> 6, ow = row & 63;
                int ih = (oh0 + ohl) * S - P + kh;
                int iw = ow * S - P + kw;
                s8v v = (s8v)0;
                if ((unsigned)ih < (unsigned)H && (unsigned)iw < (unsigned)W) {
                    v = *(const s8v*)(inb + ((size_t)ih * W + iw) * CI + kc * 32 + kcn * 8);
                    if (RELU_IN) {
#pragma unroll
                        for (int j = 0; j < 8; ++j) if (v[j] < (short)0) v[j] = 0;
                    }
                }
                *(s8v*)&sA[row * 40 + kcn * 8] = v;
            }
            for (int e = tid; e < CO * 4; e += 256) {
                int co = e >> 2, kcn = e & 3;
                *(s8v*)&sB[co * 40 + kcn * 8] =
                    *(const s8v*)(wp + (size_t)co * CI + kc * 32 + kcn * 8);
            }
            __syncthreads();
            s8v a0 = *(const s8v*)&sA[(w * 32 + rl) * 40 + qd * 8];
            s8v a1 = *(const s8v*)&sA[(w * 32 + 16 + rl) * 40 + qd * 8];
#pragma unroll
            for (int nt = 0; nt < NT; ++nt) {
                s8v b = *(const s8v*)&sB[(nt * 16 + rl) * 40 + qd * 8];
                acc0[nt] = mfma16(a0, b, acc0[nt]);
                acc1[nt] = mfma16(a1, b, acc1[nt]);
            }
        }
    }

#pragma unroll
    for (int sub = 0; sub < 2; ++sub) {
#pragma unroll
        for (int rg = 0; rg < 4; ++rg) {
            int m = w * 32 + sub * 16 + qd * 4 + rg;
            int ohl = m >> 6, ow = m & 63;
            size_t pb = ((size_t)n * 4096 + (size_t)(oh0 + ohl) * 64 + ow) * CO;
#pragma unroll
            for (int nt = 0; nt < NT; ++nt) {
                int co = nt * 16 + rl;
                float v = sub ? acc1[nt][rg] : acc0[nt][rg];
                if (bias) v += bias[co];
                if (RES) v += b2f(res[pb + co]);
                if (RELU_OUT) v = fmaxf(v, 0.f);
                if (OUT_F32) ((float*)outv)[pb + co] = v;
                else         ((short*)outv)[pb + co] = f2b(v);
            }
        }
    }
}

// ---------------------------------------------------------------------------
// 3x3 s1 p1 MFMA conv with halo-tile LDS: input staged ONCE per 32-ci chunk
// (4 rows x 66 cols), all 9 taps read shifted LDS; B-frags direct from
// global (L2-hot [tap][co][ci] weights). 144 MFMAs/wave per barrier-pair.
// ---------------------------------------------------------------------------
template<int CI, int CO, bool RELU_IN, bool RELU_OUT, bool RES, bool OUT_F32>
__global__ __launch_bounds__(256)
void mconv3_k(const short* __restrict__ in, const short* __restrict__ wt,
              const float* __restrict__ bias, const short* __restrict__ res,
              void* __restrict__ outv)
{
    constexpr int NT = CO / 16;
    constexpr int KC = CI / 32;
    __shared__ short sA[4 * 68 * 40];     // [row][col] cells of 32ci (pad 40)

    const int tid = threadIdx.x;
    const int oh0 = blockIdx.x * 2;
    const int n   = blockIdx.y;
    const short* inb = in + (size_t)n * 4096 * CI;
    const int w = tid >> 6, l = tid & 63, rl = l & 15, qd = l >> 4;

    const int m0 = w * 32 + rl, m1 = m0 + 16;
    const int base0 = (((m0 >> 6) * 68) + (m0 & 63)) * 40 + qd * 8;
    const int base1 = (((m1 >> 6) * 68) + (m1 & 63)) * 40 + qd * 8;

    f4v acc0[NT], acc1[NT];
#pragma unroll
    for (int nt = 0; nt < NT; ++nt) { acc0[nt] = (f4v)0.f; acc1[nt] = (f4v)0.f; }

    for (int kc = 0; kc < KC; ++kc) {
        __syncthreads();
        // stage halo: rows oh0-1..oh0+2, cols -1..64  (264 cells x 4 s8v)
        for (int e = tid; e < 1056; e += 256) {
            int cell = e >> 2, kcn = e & 3;
            int row = cell / 66, col = cell - row * 66;
            int ih = oh0 - 1 + row;
            int iw = col - 1;
            s8v v = (s8v)0;
            if ((unsigned)ih < 64u && (unsigned)iw < 64u) {
                v = *(const s8v*)(inb + ((size_t)ih * 64 + iw) * CI + kc * 32 + kcn * 8);
                if (RELU_IN) {
#pragma unroll
                    for (int j = 0; j < 8; ++j) if (v[j] < (short)0) v[j] = 0;
                }
            }
            *(s8v*)&sA[(row * 68 + col) * 40 + kcn * 8] = v;
        }
        __syncthreads();

#pragma unroll
        for (int tap = 0; tap < 9; ++tap) {
            const int kh = tap / 3, kw = tap % 3;
            const int toff = (kh * 68 + kw) * 40;
            s8v a0 = *(const s8v*)&sA[base0 + toff];
            s8v a1 = *(const s8v*)&sA[base1 + toff];
            const short* wp = wt + ((size_t)tap * CO + rl) * CI + kc * 32 + qd * 8;
#pragma unroll
            for (int nt = 0; nt < NT; ++nt) {
                s8v b = *(const s8v*)(wp + (size_t)nt * 16 * CI);
                acc0[nt] = mfma16(a0, b, acc0[nt]);
                acc1[nt] = mfma16(a1, b, acc1[nt]);
            }
        }
    }

#pragma unroll
    for (int sub = 0; sub < 2; ++sub) {
#pragma unroll
        for (int rg = 0; rg < 4; ++rg) {
            int m = w * 32 + sub * 16 + qd * 4 + rg;
            int ohl = m >> 6, ow = m & 63;
            size_t pb = ((size_t)n * 4096 + (size_t)(oh0 + ohl) * 64 + ow) * CO;
#pragma unroll
            for (int nt = 0; nt < NT; ++nt) {
                int co = nt * 16 + rl;
                float v = sub ? acc1[nt][rg] : acc0[nt][rg];
                if (bias) v += bias[co];
                if (RES) v += b2f(res[pb + co]);
                if (RELU_OUT) v = fmaxf(v, 0.f);
                if (OUT_F32) ((float*)outv)[pb + co] = v;
                else         ((short*)outv)[pb + co] = f2b(v);
            }
        }
    }
}

// ---------------------------------------------------------------------------
// ConvT1 as parity conv (MFMA): in NHWC bf16 (64,64,128) -> out (128,128,64)
// ---------------------------------------------------------------------------
__global__ __launch_bounds__(256)
void mct1_k(const short* __restrict__ in, const short* __restrict__ wt,
            const float* __restrict__ bias, short* __restrict__ out)
{
    __shared__ short sA[128 * 40];
    __shared__ short sB[64 * 40];
    const int tid = threadIdx.x;
    const int bx = blockIdx.x;
    const int n  = blockIdx.y;
    const int P  = bx & 1;
    const int q2 = bx >> 1;
    const int oh0 = (q2 >> 1) * 4 + (q2 & 1);
    const int p  = (oh0 + 1) & 1;
    const int ihb0 = (oh0 + 1 - p) >> 1;
    const short* inb = in + (size_t)n * 4096 * 128;
    const int w = tid >> 6, l = tid & 63, rl = l & 15, qd = l >> 4;

    f4v acc0[4], acc1[4];
#pragma unroll
    for (int nt = 0; nt < 4; ++nt) { acc0[nt] = (f4v)0.f; acc1[nt] = (f4v)0.f; }

    for (int a = 0; a < 2; ++a)
    for (int b = 0; b < 2; ++b) {
        const int kh = p + 2 * a;
        const int kw = (1 - P) + 2 * b;
        const short* wp = wt + (size_t)(kh * 4 + kw) * 64 * 128;
        for (int kc = 0; kc < 4; ++kc) {
            __syncthreads();
#pragma unroll
            for (int e = tid; e < 512; e += 256) {
                int row = e >> 2, kcn = e & 3;
                int ohl = row >> 6, j = row & 63;
                int ih = ihb0 + ohl - a;
                int iw = j + P - b;
                s8v v = (s8v)0;
                if ((unsigned)ih < 64u && (unsigned)iw < 64u)
                    v = *(const s8v*)(inb + ((size_t)(ih * 64 + iw)) * 128 + kc * 32 + kcn * 8);
                *(s8v*)&sA[row * 40 + kcn * 8] = v;
            }
            {
                int e = tid;
                if (e < 256) {
                    int co = e >> 2, kcn = e & 3;
                    *(s8v*)&sB[co * 40 + kcn * 8] =
                        *(const s8v*)(wp + (size_t)co * 128 + kc * 32 + kcn * 8);
                }
            }
            __syncthreads();
            s8v a0 = *(const s8v*)&sA[(w * 32 + rl) * 40 + qd * 8];
            s8v a1 = *(const s8v*)&sA[(w * 32 + 16 + rl) * 40 + qd * 8];
#pragma unroll
            for (int nt = 0; nt < 4; ++nt) {
                s8v bb = *(const s8v*)&sB[(nt * 16 + rl) * 40 + qd * 8];
                acc0[nt] = mfma16(a0, bb, acc0[nt]);
                acc1[nt] = mfma16(a1, bb, acc1[nt]);
            }
        }
    }

#pragma unroll
    for (int sub = 0; sub < 2; ++sub) {
#pragma unroll
        for (int rg = 0; rg < 4; ++rg) {
            int m = w * 32 + sub * 16 + qd * 4 + rg;
            int ohl = m >> 6, j = m & 63;
            int oh = oh0 + 2 * ohl, ow = 2 * j + P;
            size_t pb = (((size_t)n * 128 + oh) * 128 + ow) * 64;
#pragma unroll
            for (int nt = 0; nt < 4; ++nt) {
                int co = nt * 16 + rl;
                float v = (sub ? acc1[nt][rg] : acc0[nt][rg]) + bias[co];
                out[pb + co] = f2b(fmaxf(v, 0.f));
            }
        }
    }
}

// ---------------------------------------------------------------------------
// ConvT2: in NHWC bf16 (16,128,128,64) -> x_rec fp32 (16,256,256), k4 s2 p1.
// ---------------------------------------------------------------------------
__global__ __launch_bounds__(256)
void convt2_k(const short* __restrict__ in, const float* __restrict__ w,
              const float* __restrict__ bias, float* __restrict__ out)
{
    __shared__ float sw[16 * 64];
    const int tid = threadIdx.x;
    for (int e = tid; e < 1024; e += 256) { int ci = e >> 4, tap = e & 15; sw[tap * 64 + ci] = w[e]; }
    __syncthreads();

    const int i = blockIdx.x * 256 + tid;
    const int n = i >> 16, s = i & 65535;
    const int oh = s >> 8, ow = s & 255;

    const int p = (oh + 1) & 1, q = (ow + 1) & 1;
    const int ihb = (oh + 1 - p) >> 1, iwb = (ow + 1 - q) >> 1;

    float acc = bias[0];
#pragma unroll
    for (int a = 0; a < 2; ++a) {
        int ih = ihb - a, kh = p + 2 * a;
        bool vr = (unsigned)ih < 128u;
#pragma unroll
        for (int b = 0; b < 2; ++b) {
            int iw = iwb - b, kw = q + 2 * b;
            if (vr && (unsigned)iw < 128u) {
                const short* ip = in + (((size_t)n * 128 + ih) * 128 + iw) * 64;
                const float* wp = &sw[(kh * 4 + kw) * 64];
#pragma unroll
                for (int c = 0; c < 64; c += 8) {
                    s8v v = *(const s8v*)(ip + c);
#pragma unroll
                    for (int j = 0; j < 8; ++j) acc += b2f(v[j]) * wp[c + j];
                }
            }
        }
    }
    out[i] = acc;
}

// ---------------------------------------------------------------------------
// VQ via MFMA distance GEMM, split-bf16. 1024 blocks x 64 rows (4 waves,
// 16 rows each) for latency hiding; B-frags direct from L2-hot codebook.
// ---------------------------------------------------------------------------
__global__ __launch_bounds__(256)
void vqm_k(const float* __restrict__ z, const short* __restrict__ cbh,
           const short* __restrict__ cbl, const float* __restrict__ cbsq,
           const float* __restrict__ cb,
           float* __restrict__ quant, short* __restrict__ qb,
           int* __restrict__ idxp, int* __restrict__ counts,
           float* __restrict__ loss_sum)
{
    __shared__ int sidx[64];
    __shared__ float serr[4];
    const int tid = threadIdx.x;
    const int w = tid >> 6, l = tid & 63, rl = l & 15, qd = l >> 4;
    const int r0 = blockIdx.x * 64;
    const int rw0 = r0 + w * 16;

    // A fragments: 16 z-rows per wave, split hi/lo bf16
    s8v zh[2], zl[2];
#pragma unroll
    for (int kc = 0; kc < 2; ++kc) {
        const float4* zp = (const float4*)(z + (size_t)(rw0 + rl) * 64 + kc * 32 + qd * 8);
        float4 t0 = zp[0], t1 = zp[1];
        float vv[8] = {t0.x, t0.y, t0.z, t0.w, t1.x, t1.y, t1.z, t1.w};
        s8v hi, lo;
#pragma unroll
        for (int j = 0; j < 8; ++j) {
            short h = f2b(vv[j]);
            hi[j] = h;
            lo[j] = f2b(vv[j] - b2f(h));
        }
        zh[kc] = hi; zl[kc] = lo;
    }

    float best[4]; int bidx[4];
#pragma unroll
    for (int rg = 0; rg < 4; ++rg) { best[rg] = 3.4e38f; bidx[rg] = 0; }

#pragma unroll
    for (int ch = 0; ch < 4; ++ch) {
        f4v acc[8];
#pragma unroll
        for (int nt = 0; nt < 8; ++nt) acc[nt] = (f4v)0.f;
        float sq[8];
#pragma unroll
        for (int nt = 0; nt < 8; ++nt) sq[nt] = cbsq[ch * 128 + nt * 16 + rl];

#pragma unroll
        for (int kc = 0; kc < 2; ++kc) {
#pragma unroll
            for (int nt = 0; nt < 8; ++nt) {
                size_t co = (size_t)(ch * 128 + nt * 16 + rl) * 64 + kc * 32 + qd * 8;
                s8v bh = *(const s8v*)(cbh + co);
                s8v bl = *(const s8v*)(cbl + co);
                acc[nt] = mfma16(zh[kc], bh, acc[nt]);
                acc[nt] = mfma16(zh[kc], bl, acc[nt]);
                acc[nt] = mfma16(zl[kc], bh, acc[nt]);
            }
        }

#pragma unroll
        for (int rg = 0; rg < 4; ++rg) {
            float bd = best[rg]; int bi = bidx[rg];
#pragma unroll
            for (int nt = 0; nt < 8; ++nt) {
                float d = sq[nt] - 2.f * acc[nt][rg];
                int code = ch * 128 + nt * 16 + rl;
                if (d < bd) { bd = d; bi = code; }
            }
            best[rg] = bd; bidx[rg] = bi;
        }
    }

    // cross-lane argmin over rl (first-min tie-break)
#pragma unroll
    for (int rg = 0; rg < 4; ++rg) {
        float bd = best[rg]; int bi = bidx[rg];
#pragma unroll
        for (int off = 1; off < 16; off <<= 1) {
            float od = __shfl_xor(bd, off, 64);
            int   oi = __shfl_xor(bi, off, 64);
            if (od < bd || (od == bd && oi < bi)) { bd = od; bi = oi; }
        }
        if (rl == 0) sidx[w * 16 + qd * 4 + rg] = bi;
    }
    __syncthreads();

    // epilogue: exact fp32 error, quant (NCHW), qb (bf16 NHWC), idx, counts
    const int rr = tid & 63, quarter = tid >> 6;
    const int r = r0 + rr;
    const int bi = sidx[rr];
    const int n = r >> 12, s = r & 4095;
    const int d0 = quarter * 16;
    const float* zr = z  + (size_t)r * 64 + d0;
    const float* cr = cb + (size_t)bi * 64 + d0;
    short* qrow = qb + (size_t)r * 64 + d0;
    float err = 0.f;
#pragma unroll
    for (int g = 0; g < 2; ++g) {
        s8v qv;
#pragma unroll
        for (int j = 0; j < 8; ++j) {
            int d = g * 8 + j;
            float c = cr[d];
            float dd = zr[d] - c;
            err += dd * dd;
            qv[j] = f2b(c);
            quant[((size_t)((n << 6) + d0 + d)) * 4096 + s] = c;
        }
        *(s8v*)(qrow + g * 8) = qv;
    }
#pragma unroll
    for (int o = 32; o; o >>= 1) err += __shfl_down(err, o, 64);
    if (l == 0) serr[w] = err;
    if (tid < 64) {
        idxp[r0 + tid] = sidx[tid];
        atomicAdd(&counts[sidx[tid]], 1);
    }
    __syncthreads();
    if (tid == 0) atomicAdd(loss_sum, serr[0] + serr[1] + serr[2] + serr[3]);
}

__global__ __launch_bounds__(512)
void fin_k(const int* __restrict__ counts, const float* __restrict__ loss_sum,
           float* out_loss, float* out_perp)
{
    __shared__ float red[512];
    const int t = threadIdx.x;
    float avg = (float)counts[t] * (1.0f / 65536.0f);
    red[t] = avg * logf(avg + 1e-10f);
    __syncthreads();
    for (int st = 256; st > 0; st >>= 1) {
        if (t < st) red[t] += red[t + st];
        __syncthreads();
    }
    if (t == 0) {
        *out_perp = expf(-red[0]);
        *out_loss = loss_sum[0] * (1.25f / 4194304.0f);
    }
}

__global__ __launch_bounds__(256)
void enc_k(const int* __restrict__ idxp, float4* __restrict__ enc)
{
    int i = blockIdx.x * 256 + threadIdx.x;
    int r = i >> 7, c4 = (i & 127) * 4;
    int k = idxp[r];
    float4 v;
    v.x = (k == c4)     ? 1.f : 0.f;
    v.y = (k == c4 + 1) ? 1.f : 0.f;
    v.z = (k == c4 + 2) ? 1.f : 0.f;
    v.w = (k == c4 + 3) ? 1.f : 0.f;
    enc[i] = v;
}

// ---------------------------------------------------------------------------
extern "C" void kernel_launch(void* const* d_in, const int* in_sizes, int n_in,
                              void* d_out, int out_size, void* d_ws, size_t ws_size,
                              hipStream_t stream)
{
    const float* x    = (const float*)d_in[0];
    const float* ew1  = (const float*)d_in[1];
    const float* eb1  = (const float*)d_in[2];
    const float* ew2  = (const float*)d_in[3];
    const float* eb2  = (const float*)d_in[4];
    const float* ew3  = (const float*)d_in[5];
    const float* eb3  = (const float*)d_in[6];
    const float* er1a = (const float*)d_in[7];
    const float* er1b = (const float*)d_in[8];
    const float* er2a = (const float*)d_in[9];
    const float* er2b = (const float*)d_in[10];
    const float* pw   = (const float*)d_in[11];
    const float* pb   = (const float*)d_in[12];
    const float* cb   = (const float*)d_in[13];
    const float* dw1w = (const float*)d_in[14];
    const float* db1  = (const float*)d_in[15];
    const float* dr1a = (const float*)d_in[16];
    const float* dr1b = (const float*)d_in[17];
    const float* dr2a = (const float*)d_in[18];
    const float* dr2b = (const float*)d_in[19];
    const float* dtw1 = (const float*)d_in[20];
    const float* dtb1 = (const float*)d_in[21];
    const float* dtw2 = (const float*)d_in[22];
    const float* dtb2 = (const float*)d_in[23];

    char* wsb = (char*)d_ws;
    short* wbase = (short*)wsb;
    short* wt2   = wbase;
    short* wt3   = wbase + 131072;
    short* wr1a  = wbase + 278528;
    short* wr1b  = wbase + 315392;
    short* wr2a  = wbase + 319488;
    short* wr2b  = wbase + 356352;
    short* wpwt  = wbase + 360448;
    short* wd1   = wbase + 368640;
    short* wdr1a = wbase + 442368;
    short* wdr1b = wbase + 479232;
    short* wdr2a = wbase + 483328;
    short* wdr2b = wbase + 520192;
    short* wtt1  = wbase + 524288;

    short* h2   = (short*)(wsb + 1310720);
    short* buf  = (short*)(wsb + 18087936);
    short* mid  = (short*)(wsb + 34865152);
    short* qb   = (short*)(wsb + 39059456);
    float* z    = (float*)(wsb + 47448064);
    int*   idx  = (int*)  (wsb + 64225280);
    int*   counts   = (int*)(wsb + 64487424);
    float* loss_sum = (float*)(wsb + 64489472);
    if (ws_size < (size_t)64489480) return;

    float* out    = (float*)d_out;
    float* o_loss = out;
    float* xrec   = out + 1;
    float* o_perp = out + 1048577;
    float* enc    = out + 1048578;
    float* quant  = out + 34603010;
    short* h1  = (short*)((char*)d_out + (size_t)1048580 * 4);
    short* dt1 = h1 + 16777216;
    char*  encB = (char*)d_out + (size_t)1048580 * 4;
    short* cbh  = (short*)(encB + ((size_t)120 << 20));
    short* cbl  = cbh + 32768;
    float* cbsq = (float*)(cbl + 32768);

    hipMemsetAsync(counts, 0, 516 * 4, stream);

    WtArgs wa;
    wa.d[0]  = { ew2,  128,  64, 16, 0, 0      };
    wa.d[1]  = { ew3,  128, 128,  9, 0, 131072 };
    wa.d[2]  = { er1a,  32, 128,  9, 0, 278528 };
    wa.d[3]  = { er1b, 128,  32,  1, 0, 315392 };
    wa.d[4]  = { er2a,  32, 128,  9, 0, 319488 };
    wa.d[5]  = { er2b, 128,  32,  1, 0, 356352 };
    wa.d[6]  = { pw,    64, 128,  1, 0, 360448 };
    wa.d[7]  = { dw1w, 128,  64,  9, 0, 368640 };
    wa.d[8]  = { dr1a,  32, 128,  9, 0, 442368 };
    wa.d[9]  = { dr1b, 128,  32,  1, 0, 479232 };
    wa.d[10] = { dr2a,  32, 128,  9, 0, 483328 };
    wa.d[11] = { dr2b, 128,  32,  1, 0, 520192 };
    wa.d[12] = { dtw1,  64, 128, 16, 1, 524288 };
    wa.total = 655360;
    wtall_k<<<dim3(2560), TPB, 0, stream>>>(wa, wbase);
    cbprep_k<<<dim3(2), TPB, 0, stream>>>(cb, cbh, cbl, cbsq);

    // ---- encoder ----
    conv1_k<<<dim3(128, 16), TPB, 0, stream>>>(x, ew1, eb1, h1);
    mconv_k<4,4,2,1, 64,128,false,true ,false,false><<<dim3(32,16), TPB, 0, stream>>>(h1,  wt2,  eb2, nullptr, h2);
    mconv3_k<128,128,false,false,false,false><<<dim3(32,16), TPB, 0, stream>>>(h2,  wt3,  eb3, nullptr, buf);
    mconv3_k<128, 32,true ,true ,false,false><<<dim3(32,16), TPB, 0, stream>>>(buf, wr1a, nullptr, nullptr, mid);
    mconv_k<1,1,1,0, 32,128,false,false,true ,false><<<dim3(32,16), TPB, 0, stream>>>(mid, wr1b, nullptr, buf, buf);
    mconv3_k<128, 32,true ,true ,false,false><<<dim3(32,16), TPB, 0, stream>>>(buf, wr2a, nullptr, nullptr, mid);
    mconv_k<1,1,1,0, 32,128,false,false,true ,false><<<dim3(32,16), TPB, 0, stream>>>(mid, wr2b, nullptr, buf, buf);
    mconv_k<1,1,1,0,128, 64,true ,false,false,true ><<<dim3(32,16), TPB, 0, stream>>>(buf, wpwt, pb, nullptr, z);

    // ---- VQ ----
    vqm_k<<<dim3(1024), TPB, 0, stream>>>(z, cbh, cbl, cbsq, cb, quant, qb, idx, counts, loss_sum);
    fin_k<<<dim3(1), 512, 0, stream>>>(counts, loss_sum, o_loss, o_perp);

    // ---- decoder ----
    mconv3_k< 64,128,false,false,false,false><<<dim3(32,16), TPB, 0, stream>>>(qb,  wd1,   db1, nullptr, buf);
    mconv3_k<128, 32,true ,true ,false,false><<<dim3(32,16), TPB, 0, stream>>>(buf, wdr1a, nullptr, nullptr, mid);
    mconv_k<1,1,1,0, 32,128,false,false,true ,false><<<dim3(32,16), TPB, 0, stream>>>(mid, wdr1b, nullptr, buf, buf);
    mconv3_k<128, 32,true ,true ,false,false><<<dim3(32,16), TPB, 0, stream>>>(buf, wdr2a, nullptr, nullptr, mid);
    mconv_k<1,1,1,0, 32,128,false,false,true ,false><<<dim3(32,16), TPB, 0, stream>>>(mid, wdr2b, nullptr, buf, buf);
    mct1_k<<<dim3(128, 16), TPB, 0, stream>>>(buf, wtt1, dtb1, dt1);
    convt2_k<<<dim3(4096), TPB, 0, stream>>>(dt1, dtw2, dtb2, xrec);

    // ---- encodings (last) ----
    enc_k<<<dim3(32768), TPB, 0, stream>>>(idx, (float4*)enc);
}

// Round 6
// 647.171 us; speedup vs baseline: 1.3776x; 1.3776x over previous
//
#include <hip/hip_runtime.h>

#define TPB 256

typedef __attribute__((ext_vector_type(8))) short s8v;
typedef __attribute__((ext_vector_type(4))) float f4v;
typedef __bf16 bf16x8v __attribute__((ext_vector_type(8)));

__device__ inline short f2b(float f) {
    unsigned u = __builtin_bit_cast(unsigned, f);
    unsigned r = (u + 0x7FFF + ((u >> 16) & 1)) >> 16;
    return (short)r;
}
__device__ inline float b2f(short s) {
    unsigned u = ((unsigned)(unsigned short)s) << 16;
    return __builtin_bit_cast(float, u);
}
__device__ inline f4v mfma16(s8v a, s8v b, f4v c) {
    return __builtin_amdgcn_mfma_f32_16x16x32_bf16(
        __builtin_bit_cast(bf16x8v, a), __builtin_bit_cast(bf16x8v, b), c, 0, 0, 0);
}

// ---------------------------------------------------------------------------
// Weight prep: OIHW/IOHW fp32 -> MFMA-fragment-packed bf16:
// dst[((tap*KC+kc)*NT + nt)*512 + lane*8 + j] = W[nt*16+rl][kc*32+qd*8+j] @tap
// so a B-fragment load is base + lane*16B (fully coalesced 1024-B wave read).
// ---------------------------------------------------------------------------
struct WtDesc { const float* src; int CO, CI, T, iohw, start; };
struct WtArgs { WtDesc d[13]; int total; };

__global__ __launch_bounds__(256)
void wtall_k(WtArgs a, short* dst)
{
    int i = blockIdx.x * 256 + threadIdx.x;
    if (i >= a.total) return;
    int s = 0;
    for (int j = 1; j < 13; ++j) if (i >= a.d[j].start) s = j;
    int off = i - a.d[s].start;
    int CI = a.d[s].CI, CO = a.d[s].CO, T = a.d[s].T;
    int KC = CI >> 5, NT = CO >> 4;
    int j    = off & 7;
    int lane = (off >> 3) & 63;
    int rl = lane & 15, qd = lane >> 4;
    int blk = off >> 9;
    int nt  = blk % NT;
    int rest = blk / NT;
    int kc  = rest % KC;
    int tap = rest / KC;
    int co = nt * 16 + rl;
    int ci = kc * 32 + qd * 8 + j;
    float v = a.d[s].iohw ? a.d[s].src[(ci * CO + co) * T + tap]
                          : a.d[s].src[(co * CI + ci) * T + tap];
    dst[i] = f2b(v);
}

// Codebook prep: one thread per code. Emits fragment-packed hi/lo bf16
// ([kc][nt32][512] blocks) + |c|^2 fp32.
__global__ __launch_bounds__(256)
void cbprep_k(const float* __restrict__ cb, short* __restrict__ cbh,
              short* __restrict__ cbl, float* __restrict__ cbsq)
{
    int c = blockIdx.x * 256 + threadIdx.x;   // 0..511
    const float* src = cb + (size_t)c * 64;
    const int nt = c >> 4, rl = c & 15;
    float sq = 0.f;
    for (int d = 0; d < 64; ++d) {
        float v = src[d];
        sq += v * v;
        short h = f2b(v);
        short lo = f2b(v - b2f(h));
        int kc = d >> 5, qd = (d >> 3) & 3, j = d & 7;
        int pos = ((kc * 32 + nt) << 9) + ((qd * 16 + rl) << 3) + j;
        cbh[pos] = h;
        cbl[pos] = lo;
    }
    cbsq[c] = sq;
}

// ---------------------------------------------------------------------------
// conv1: x (16,1,256,256) fp32 -> h1 NHWC bf16 (16,128,128,64), k4 s2 p1.
// ---------------------------------------------------------------------------
__global__ __launch_bounds__(256)
void conv1_k(const float* __restrict__ x, const float* __restrict__ w,
             const float* __restrict__ bias, short* __restrict__ out)
{
    __shared__ float sx[4 * 256];
    const int tid = threadIdx.x;
    const int oh = blockIdx.x, n = blockIdx.y;
    const int co = tid & 63, wv = tid >> 6;

    float wr[16];
#pragma unroll
    for (int t = 0; t < 16; ++t) wr[t] = w[co * 16 + t];
    const float b = bias[co];

    const float* xp = x + (size_t)n * 65536;
    for (int e = tid; e < 1024; e += 256) {
        int kh = e >> 8, col = e & 255;
        int ih = oh * 2 - 1 + kh;
        sx[e] = ((unsigned)ih < 256u) ? xp[ih * 256 + col] : 0.f;
    }
    __syncthreads();

    short* op = out + (((size_t)n * 128 + oh) * 128) * 64 + co;
#pragma unroll 4
    for (int i = 0; i < 32; ++i) {
        int ow = wv * 32 + i;
        int iwb = ow * 2 - 1;
        float acc = b;
#pragma unroll
        for (int kh = 0; kh < 4; ++kh) {
#pragma unroll
            for (int kw = 0; kw < 4; ++kw) {
                int iw = iwb + kw;
                float v = ((unsigned)iw < 256u) ? sx[kh * 256 + iw] : 0.f;
                acc = fmaf(v, wr[kh * 4 + kw], acc);
            }
        }
        op[(size_t)ow * 64] = f2b(fmaxf(acc, 0.f));
    }
}

// ---------------------------------------------------------------------------
// 3x3 s1 p1 MFMA conv, halo-LDS A + packed-B direct from global.
// Block: M=128 (2 oh rows), N=CO. 4 waves in 2x2: 64(M)x(CO/2)(N) tiles.
// ---------------------------------------------------------------------------
template<int CI, int CO, bool RELU_IN, bool RELU_OUT, bool OUT_F32>
__global__ __launch_bounds__(256)
void pconv3_k(const short* __restrict__ in, const short* __restrict__ wt,
              const float* __restrict__ bias, void* __restrict__ outv)
{
    constexpr int KC = CI / 32, NT = CO / 16;
    constexpr int NT2 = (NT >= 2) ? NT / 2 : 1;
    __shared__ short sA[4 * 68 * 40];

    const int tid = threadIdx.x;
    const int oh0 = blockIdx.x * 2;
    const int n   = blockIdx.y;
    const short* inb = in + (size_t)n * 4096 * CI;
    const int w = tid >> 6, l = tid & 63, rl = l & 15, qd = l >> 4;
    const int mh = w & 1, nh = w >> 1;

    f4v acc[4][NT2];
#pragma unroll
    for (int a4 = 0; a4 < 4; ++a4)
#pragma unroll
        for (int nt = 0; nt < NT2; ++nt) acc[a4][nt] = (f4v)0.f;

    for (int kc = 0; kc < KC; ++kc) {
        __syncthreads();
        for (int e = tid; e < 1056; e += 256) {
            int cell = e >> 2, kcn = e & 3;
            int row = cell / 66, col = cell - row * 66;
            int ih = oh0 - 1 + row, iw = col - 1;
            s8v v = (s8v)0;
            if ((unsigned)ih < 64u && (unsigned)iw < 64u) {
                v = *(const s8v*)(inb + ((size_t)ih * 64 + iw) * CI + kc * 32 + kcn * 8);
                if (RELU_IN) {
#pragma unroll
                    for (int j = 0; j < 8; ++j) if (v[j] < (short)0) v[j] = 0;
                }
            }
            *(s8v*)&sA[(row * 68 + col) * 40 + kcn * 8] = v;
        }
        __syncthreads();

#pragma unroll
        for (int tap = 0; tap < 9; ++tap) {
            const int kh = tap / 3, kw = tap % 3;
            s8v af[4];
#pragma unroll
            for (int a4 = 0; a4 < 4; ++a4)
                af[a4] = *(const s8v*)&sA[((mh + kh) * 68 + a4 * 16 + rl + kw) * 40 + qd * 8];
            const short* wb = wt + (((size_t)(tap * KC + kc) * NT + nh * NT2) << 9) + l * 8;
#pragma unroll
            for (int nt = 0; nt < NT2; ++nt) {
                s8v b = *(const s8v*)(wb + ((size_t)nt << 9));
#pragma unroll
                for (int a4 = 0; a4 < 4; ++a4)
                    acc[a4][nt] = mfma16(af[a4], b, acc[a4][nt]);
            }
        }
    }

#pragma unroll
    for (int a4 = 0; a4 < 4; ++a4) {
#pragma unroll
        for (int rg = 0; rg < 4; ++rg) {
            int ow = a4 * 16 + qd * 4 + rg;
            size_t row = (size_t)n * 4096 + (size_t)(oh0 + mh) * 64 + ow;
#pragma unroll
            for (int nt = 0; nt < NT2; ++nt) {
                int co = nh * NT2 * 16 + nt * 16 + rl;
                float v = acc[a4][nt][rg];
                if (bias) v += bias[co];
                if (RELU_OUT) v = fmaxf(v, 0.f);
                if (OUT_F32) ((float*)outv)[row * CO + co] = v;
                else         ((short*)outv)[row * CO + co] = f2b(v);
            }
        }
    }
}

// ---------------------------------------------------------------------------
// 1x1 MFMA conv (pure GEMM). Block: M=128 rows, N=CO. Optional residual.
// ---------------------------------------------------------------------------
template<int CI, int CO, bool RELU_IN, bool RELU_OUT, bool RES, bool OUT_F32>
__global__ __launch_bounds__(256)
void pconv1_k(const short* __restrict__ in, const short* __restrict__ wt,
              const float* __restrict__ bias, const short* __restrict__ res,
              void* __restrict__ outv)
{
    constexpr int KC = CI / 32, NT = CO / 16;
    constexpr int NT2 = (NT >= 2) ? NT / 2 : 1;
    __shared__ short sA[128 * 40];

    const int tid = threadIdx.x;
    const size_t r0 = (size_t)blockIdx.x * 128;
    const int w = tid >> 6, l = tid & 63, rl = l & 15, qd = l >> 4;
    const int mh = w & 1, nh = w >> 1;

    f4v acc[4][NT2];
#pragma unroll
    for (int a4 = 0; a4 < 4; ++a4)
#pragma unroll
        for (int nt = 0; nt < NT2; ++nt) acc[a4][nt] = (f4v)0.f;

    for (int kc = 0; kc < KC; ++kc) {
        __syncthreads();
        for (int e = tid; e < 512; e += 256) {
            int row = e >> 2, kcn = e & 3;
            s8v v = *(const s8v*)(in + (r0 + row) * CI + kc * 32 + kcn * 8);
            if (RELU_IN) {
#pragma unroll
                for (int j = 0; j < 8; ++j) if (v[j] < (short)0) v[j] = 0;
            }
            *(s8v*)&sA[row * 40 + kcn * 8] = v;
        }
        __syncthreads();

        s8v af[4];
#pragma unroll
        for (int a4 = 0; a4 < 4; ++a4)
            af[a4] = *(const s8v*)&sA[(mh * 64 + a4 * 16 + rl) * 40 + qd * 8];
        const short* wb = wt + (((size_t)kc * NT + nh * NT2) << 9) + l * 8;
#pragma unroll
        for (int nt = 0; nt < NT2; ++nt) {
            s8v b = *(const s8v*)(wb + ((size_t)nt << 9));
#pragma unroll
            for (int a4 = 0; a4 < 4; ++a4)
                acc[a4][nt] = mfma16(af[a4], b, acc[a4][nt]);
        }
    }

#pragma unroll
    for (int a4 = 0; a4 < 4; ++a4) {
#pragma unroll
        for (int rg = 0; rg < 4; ++rg) {
            size_t row = r0 + mh * 64 + a4 * 16 + qd * 4 + rg;
#pragma unroll
            for (int nt = 0; nt < NT2; ++nt) {
                int co = nh * NT2 * 16 + nt * 16 + rl;
                float v = acc[a4][nt][rg];
                if (bias) v += bias[co];
                if (RES) v += b2f(res[row * CO + co]);
                if (RELU_OUT) v = fmaxf(v, 0.f);
                if (OUT_F32) ((float*)outv)[row * CO + co] = v;
                else         ((short*)outv)[row * CO + co] = f2b(v);
            }
        }
    }
}

// ---------------------------------------------------------------------------
// conv2: k4 s2 p1, CI=64 -> CO=128, in h1 (16,128,128,64) -> h2 (16,64,64,128).
// Parity-split halo (unit-stride LDS reads per tap). Block M=64 (1 oh row).
// ---------------------------------------------------------------------------
__global__ __launch_bounds__(256)
void pconv2_k(const short* __restrict__ in, const short* __restrict__ wt,
              const float* __restrict__ bias, short* __restrict__ out)
{
    __shared__ short sA[2 * 4 * 66 * 40];   // [par][hr][c] cells of 32ci
    const int tid = threadIdx.x;
    const int oh = blockIdx.x, n = blockIdx.y;
    const short* inb = in + (size_t)n * 16384 * 64;
    const int w = tid >> 6, l = tid & 63, rl = l & 15, qd = l >> 4;
    const int mh = w & 1, nh = w >> 1;

    f4v acc[2][4];
#pragma unroll
    for (int a2 = 0; a2 < 2; ++a2)
#pragma unroll
        for (int nt = 0; nt < 4; ++nt) acc[a2][nt] = (f4v)0.f;

    for (int kc = 0; kc < 2; ++kc) {
        __syncthreads();
        for (int e = tid; e < 2112; e += 256) {
            int cell = e >> 2, kcn = e & 3;
            int par = cell / 264;
            int rem = cell - par * 264;
            int hr = rem / 66, c = rem - hr * 66;
            int iw = par ? (2 * c - 1) : (2 * c);
            int ih = oh * 2 - 1 + hr;
            s8v v = (s8v)0;
            if ((unsigned)ih < 128u && (unsigned)iw < 128u)
                v = *(const s8v*)(inb + ((size_t)ih * 128 + iw) * 64 + kc * 32 + kcn * 8);
            *(s8v*)&sA[((par * 4 + hr) * 66 + c) * 40 + kcn * 8] = v;
        }
        __syncthreads();

#pragma unroll
        for (int tap = 0; tap < 16; ++tap) {
            const int kh = tap >> 2, kw = tap & 3;
            const int par = 1 - (kw & 1), cofs = kw >> 1;
            s8v af[2];
#pragma unroll
            for (int a2 = 0; a2 < 2; ++a2) {
                int ow = mh * 32 + a2 * 16 + rl;
                af[a2] = *(const s8v*)&sA[((par * 4 + kh) * 66 + ow + cofs) * 40 + qd * 8];
            }
            const short* wb = wt + (((size_t)(tap * 2 + kc) * 8 + nh * 4) << 9) + l * 8;
#pragma unroll
            for (int nt = 0; nt < 4; ++nt) {
                s8v b = *(const s8v*)(wb + ((size_t)nt << 9));
#pragma unroll
                for (int a2 = 0; a2 < 2; ++a2)
                    acc[a2][nt] = mfma16(af[a2], b, acc[a2][nt]);
            }
        }
    }

#pragma unroll
    for (int a2 = 0; a2 < 2; ++a2) {
#pragma unroll
        for (int rg = 0; rg < 4; ++rg) {
            int ow = mh * 32 + a2 * 16 + qd * 4 + rg;
            size_t row = (size_t)n * 4096 + (size_t)oh * 64 + ow;
#pragma unroll
            for (int nt = 0; nt < 4; ++nt) {
                int co = nh * 64 + nt * 16 + rl;
                float v = acc[a2][nt][rg] + bias[co];
                out[row * 128 + co] = f2b(fmaxf(v, 0.f));
            }
        }
    }
}

// ---------------------------------------------------------------------------
// ConvT1 (k4 s2 p1, 128->64): parity conv w/ halo. in (16,64,64,128) NHWC
// -> dt1 (16,128,128,64) NHWC. Block: ow-parity P, rows oh0 & oh0+2, M=128.
// ---------------------------------------------------------------------------
__global__ __launch_bounds__(256)
void pct1_k(const short* __restrict__ in, const short* __restrict__ wt,
            const float* __restrict__ bias, short* __restrict__ out)
{
    __shared__ short sA[3 * 66 * 40];
    const int tid = threadIdx.x;
    const int bx = blockIdx.x, n = blockIdx.y;
    const int P = bx & 1;
    const int q2 = bx >> 1;
    const int oh0 = (q2 >> 1) * 4 + (q2 & 1);
    const int p = (oh0 + 1) & 1;
    const int ihb0 = (oh0 + 1 - p) >> 1;
    const short* inb = in + (size_t)n * 4096 * 128;
    const int w = tid >> 6, l = tid & 63, rl = l & 15, qd = l >> 4;
    const int mh = w & 1, nh = w >> 1;

    f4v acc[4][2];
#pragma unroll
    for (int a4 = 0; a4 < 4; ++a4)
#pragma unroll
        for (int nt = 0; nt < 2; ++nt) acc[a4][nt] = (f4v)0.f;

    for (int kc = 0; kc < 4; ++kc) {
        __syncthreads();
        for (int e = tid; e < 792; e += 256) {
            int cell = e >> 2, kcn = e & 3;
            int hr = cell / 66, c = cell - hr * 66;
            int ih = ihb0 - 1 + hr, iw = c - 1;
            s8v v = (s8v)0;
            if ((unsigned)ih < 64u && (unsigned)iw < 64u)
                v = *(const s8v*)(inb + ((size_t)ih * 64 + iw) * 128 + kc * 32 + kcn * 8);
            *(s8v*)&sA[(hr * 66 + c) * 40 + kcn * 8] = v;
        }
        __syncthreads();

#pragma unroll
        for (int a = 0; a < 2; ++a)
#pragma unroll
        for (int b = 0; b < 2; ++b) {
            const int kh = p + 2 * a;
            const int kw = (1 - P) + 2 * b;
            const int tap = kh * 4 + kw;
            const int hrw = mh + 1 - a;
            s8v af[4];
#pragma unroll
            for (int a4 = 0; a4 < 4; ++a4)
                af[a4] = *(const s8v*)&sA[(hrw * 66 + a4 * 16 + rl + P - b + 1) * 40 + qd * 8];
            const short* wb = wt + (((size_t)(tap * 4 + kc) * 4 + nh * 2) << 9) + l * 8;
#pragma unroll
            for (int nt = 0; nt < 2; ++nt) {
                s8v bb = *(const s8v*)(wb + ((size_t)nt << 9));
#pragma unroll
                for (int a4 = 0; a4 < 4; ++a4)
                    acc[a4][nt] = mfma16(af[a4], bb, acc[a4][nt]);
            }
        }
    }

#pragma unroll
    for (int a4 = 0; a4 < 4; ++a4) {
#pragma unroll
        for (int rg = 0; rg < 4; ++rg) {
            int j = a4 * 16 + qd * 4 + rg;
            int oh = oh0 + 2 * mh, ow = 2 * j + P;
            size_t pb = (((size_t)n * 128 + oh) * 128 + ow) * 64;
#pragma unroll
            for (int nt = 0; nt < 2; ++nt) {
                int co = nh * 32 + nt * 16 + rl;
                float v = acc[a4][nt][rg] + bias[co];
                out[pb + co] = f2b(fmaxf(v, 0.f));
            }
        }
    }
}

// ---------------------------------------------------------------------------
// ConvT2: in NHWC bf16 (16,128,128,64) -> x_rec fp32 (16,256,256), k4 s2 p1.
// ---------------------------------------------------------------------------
__global__ __launch_bounds__(256)
void convt2_k(const short* __restrict__ in, const float* __restrict__ w,
              const float* __restrict__ bias, float* __restrict__ out)
{
    __shared__ float sw[16 * 64];
    const int tid = threadIdx.x;
    for (int e = tid; e < 1024; e += 256) { int ci = e >> 4, tap = e & 15; sw[tap * 64 + ci] = w[e]; }
    __syncthreads();

    const int i = blockIdx.x * 256 + tid;
    const int n = i >> 16, s = i & 65535;
    const int oh = s >> 8, ow = s & 255;

    const int p = (oh + 1) & 1, q = (ow + 1) & 1;
    const int ihb = (oh + 1 - p) >> 1, iwb = (ow + 1 - q) >> 1;

    float acc = bias[0];
#pragma unroll
    for (int a = 0; a < 2; ++a) {
        int ih = ihb - a, kh = p + 2 * a;
        bool vr = (unsigned)ih < 128u;
#pragma unroll
        for (int b = 0; b < 2; ++b) {
            int iw = iwb - b, kw = q + 2 * b;
            if (vr && (unsigned)iw < 128u) {
                const short* ip = in + (((size_t)n * 128 + ih) * 128 + iw) * 64;
                const float* wp = &sw[(kh * 4 + kw) * 64];
#pragma unroll
                for (int c = 0; c < 64; c += 8) {
                    s8v v = *(const s8v*)(ip + c);
#pragma unroll
                    for (int j = 0; j < 8; ++j) acc += b2f(v[j]) * wp[c + j];
                }
            }
        }
    }
    out[i] = acc;
}

// ---------------------------------------------------------------------------
// VQ: MFMA distance GEMM, split-bf16, fully-coalesced memory paths.
// 1024 blocks x 64 rows. z + codebook chunks staged in LDS; cooperative
// per-row epilogue (lane = channel); no global atomics.
// ---------------------------------------------------------------------------
__global__ __launch_bounds__(256)
void vqm_k(const float* __restrict__ z, const short* __restrict__ cbh,
           const short* __restrict__ cbl, const float* __restrict__ cbsq,
           const float* __restrict__ cb,
           float* __restrict__ quant, short* __restrict__ qb,
           int* __restrict__ idxp, float* __restrict__ errbuf)
{
    __shared__ float zs[64 * 68];       // 17.4 KB
    __shared__ short scb[2][8192];      // 32 KB (hi, lo) — aliased w/ qc later
    __shared__ int sidx[64];
    __shared__ float serr[4];
    float* qc = (float*)&scb[0][0];     // 64*68 f32 = 17.4 KB < 32 KB

    const int tid = threadIdx.x;
    const int w = tid >> 6, l = tid & 63, rl = l & 15, qd = l >> 4;
    const int r0 = blockIdx.x * 64;

    // stage z (coalesced)
    for (int e = tid; e < 1024; e += 256) {
        int row = e >> 4, c4 = e & 15;
        float4 t = ((const float4*)(z + (size_t)(r0 + row) * 64))[c4];
        *(float4*)&zs[row * 68 + c4 * 4] = t;
    }
    __syncthreads();

    // A fragments: wave w handles z-rows r0 + w*16 + rl; split hi/lo
    s8v zh[2], zl[2];
#pragma unroll
    for (int kc = 0; kc < 2; ++kc) {
        const float* zp = &zs[(w * 16 + rl) * 68 + kc * 32 + qd * 8];
        s8v hi, lo;
#pragma unroll
        for (int j = 0; j < 8; ++j) {
            float v = zp[j];
            short h = f2b(v);
            hi[j] = h;
            lo[j] = f2b(v - b2f(h));
        }
        zh[kc] = hi; zl[kc] = lo;
    }

    float best[4]; int bidx[4];
#pragma unroll
    for (int rg = 0; rg < 4; ++rg) { best[rg] = 3.4e38f; bidx[rg] = 0; }

    for (int ch = 0; ch < 4; ++ch) {
        __syncthreads();
        // stage codebook chunk from packed arrays (coalesced 16-B/lane)
        for (int e = tid; e < 1024; e += 256) {
            int kcL = e >> 9, rest = e & 511;
            int ntl = rest >> 6, off = rest & 63;
            int srcIdx = (kcL * 32 + ch * 8 + ntl) * 64 + off;
            *(s8v*)&scb[0][e * 8] = ((const s8v*)cbh)[srcIdx];
            *(s8v*)&scb[1][e * 8] = ((const s8v*)cbl)[srcIdx];
        }
        __syncthreads();

        float sq[8];
#pragma unroll
        for (int nt = 0; nt < 8; ++nt) sq[nt] = cbsq[ch * 128 + nt * 16 + rl];

        f4v acc[8];
#pragma unroll
        for (int nt = 0; nt < 8; ++nt) acc[nt] = (f4v)0.f;
#pragma unroll
        for (int kc = 0; kc < 2; ++kc) {
#pragma unroll
            for (int nt = 0; nt < 8; ++nt) {
                s8v bh = *(const s8v*)&scb[0][(kc * 8 + nt) * 512 + l * 8];
                s8v bl = *(const s8v*)&scb[1][(kc * 8 + nt) * 512 + l * 8];
                acc[nt] = mfma16(zh[kc], bh, acc[nt]);
                acc[nt] = mfma16(zh[kc], bl, acc[nt]);
                acc[nt] = mfma16(zl[kc], bh, acc[nt]);
            }
        }

#pragma unroll
        for (int rg = 0; rg < 4; ++rg) {
            float bd = best[rg]; int bi = bidx[rg];
#pragma unroll
            for (int nt = 0; nt < 8; ++nt) {
                float d = sq[nt] - 2.f * acc[nt][rg];
                int code = ch * 128 + nt * 16 + rl;
                if (d < bd) { bd = d; bi = code; }
            }
            best[rg] = bd; bidx[rg] = bi;
        }
    }

    // cross-lane argmin over rl (first-min tie-break)
#pragma unroll
    for (int rg = 0; rg < 4; ++rg) {
        float bd = best[rg]; int bi = bidx[rg];
#pragma unroll
        for (int off = 1; off < 16; off <<= 1) {
            float od = __shfl_xor(bd, off, 64);
            int   oi = __shfl_xor(bi, off, 64);
            if (od < bd || (od == bd && oi < bi)) { bd = od; bi = oi; }
        }
        if (rl == 0) sidx[w * 16 + qd * 4 + rg] = bi;
    }
    __syncthreads();

    // cooperative epilogue: lane = channel; all accesses coalesced
    const int n = r0 >> 12, s0 = r0 & 4095;
    float err = 0.f;
#pragma unroll 4
    for (int i = 0; i < 16; ++i) {
        int rr = w * 16 + i;
        int bi = sidx[rr];
        float c = cb[(size_t)bi * 64 + l];          // 256-B coalesced, L2-hot
        float zv = zs[rr * 68 + l];
        float dd = zv - c;
        err += dd * dd;
        qb[(size_t)(r0 + rr) * 64 + l] = f2b(c);    // 128-B coalesced
        qc[l * 68 + rr] = c;                        // LDS transpose
    }
#pragma unroll
    for (int o = 32; o; o >>= 1) err += __shfl_down(err, o, 64);
    if (l == 0) serr[w] = err;
    if (tid < 64) idxp[r0 + tid] = sidx[tid];
    __syncthreads();

    // quant NCHW stores: 256-B contiguous per instruction
#pragma unroll 4
    for (int dd = 0; dd < 16; ++dd) {
        int d = w * 16 + dd;
        quant[((size_t)(n * 64 + d)) * 4096 + s0 + l] = qc[d * 68 + l];
    }
    if (tid == 0) errbuf[blockIdx.x] = serr[0] + serr[1] + serr[2] + serr[3];
}

// loss + perplexity: counts rebuilt from idxp via LDS histogram (no atomics
// anywhere global). One block, 1024 threads.
__global__ __launch_bounds__(1024)
void fin_k(const int* __restrict__ idxp, const float* __restrict__ errbuf,
           float* out_loss, float* out_perp)
{
    __shared__ int lc[512];
    __shared__ float red[1024];
    const int t = threadIdx.x;
    if (t < 512) lc[t] = 0;
    __syncthreads();
    for (int i = t; i < 65536; i += 1024) atomicAdd(&lc[idxp[i]], 1);
    __syncthreads();
    float v = 0.f;
    if (t < 512) {
        float avg = (float)lc[t] * (1.0f / 65536.0f);
        v = avg * logf(avg + 1e-10f);
    }
    red[t] = v;
    __syncthreads();
    for (int st = 512; st; st >>= 1) { if (t < st) red[t] += red[t + st]; __syncthreads(); }
    if (t == 0) *out_perp = expf(-red[0]);
    __syncthreads();
    red[t] = errbuf[t];
    __syncthreads();
    for (int st = 512; st; st >>= 1) { if (t < st) red[t] += red[t + st]; __syncthreads(); }
    if (t == 0) *out_loss = red[0] * (1.25f / 4194304.0f);
}

__global__ __launch_bounds__(256)
void enc_k(const int* __restrict__ idxp, float4* __restrict__ enc)
{
    int i = blockIdx.x * 256 + threadIdx.x;
    int r = i >> 7, c4 = (i & 127) * 4;
    int k = idxp[r];
    float4 v;
    v.x = (k == c4)     ? 1.f : 0.f;
    v.y = (k == c4 + 1) ? 1.f : 0.f;
    v.z = (k == c4 + 2) ? 1.f : 0.f;
    v.w = (k == c4 + 3) ? 1.f : 0.f;
    enc[i] = v;
}

// ---------------------------------------------------------------------------
extern "C" void kernel_launch(void* const* d_in, const int* in_sizes, int n_in,
                              void* d_out, int out_size, void* d_ws, size_t ws_size,
                              hipStream_t stream)
{
    const float* x    = (const float*)d_in[0];
    const float* ew1  = (const float*)d_in[1];
    const float* eb1  = (const float*)d_in[2];
    const float* ew2  = (const float*)d_in[3];
    const float* eb2  = (const float*)d_in[4];
    const float* ew3  = (const float*)d_in[5];
    const float* eb3  = (const float*)d_in[6];
    const float* er1a = (const float*)d_in[7];
    const float* er1b = (const float*)d_in[8];
    const float* er2a = (const float*)d_in[9];
    const float* er2b = (const float*)d_in[10];
    const float* pw   = (const float*)d_in[11];
    const float* pb   = (const float*)d_in[12];
    const float* cb   = (const float*)d_in[13];
    const float* dw1w = (const float*)d_in[14];
    const float* db1  = (const float*)d_in[15];
    const float* dr1a = (const float*)d_in[16];
    const float* dr1b = (const float*)d_in[17];
    const float* dr2a = (const float*)d_in[18];
    const float* dr2b = (const float*)d_in[19];
    const float* dtw1 = (const float*)d_in[20];
    const float* dtb1 = (const float*)d_in[21];
    const float* dtw2 = (const float*)d_in[22];
    const float* dtb2 = (const float*)d_in[23];

    char* wsb = (char*)d_ws;
    short* wbase = (short*)wsb;
    short* wt2   = wbase;            // sizes unchanged, packed layout
    short* wt3   = wbase + 131072;
    short* wr1a  = wbase + 278528;
    short* wr1b  = wbase + 315392;
    short* wr2a  = wbase + 319488;
    short* wr2b  = wbase + 356352;
    short* wpwt  = wbase + 360448;
    short* wd1   = wbase + 368640;
    short* wdr1a = wbase + 442368;
    short* wdr1b = wbase + 479232;
    short* wdr2a = wbase + 483328;
    short* wdr2b = wbase + 520192;
    short* wtt1  = wbase + 524288;

    short* h2   = (short*)(wsb + 1310720);
    short* buf  = (short*)(wsb + 18087936);
    short* mid  = (short*)(wsb + 34865152);
    short* qb   = (short*)(wsb + 39059456);
    float* z    = (float*)(wsb + 47448064);
    int*   idx  = (int*)  (wsb + 64225280);
    if (ws_size < (size_t)64489480) return;

    float* out    = (float*)d_out;
    float* o_loss = out;
    float* xrec   = out + 1;
    float* o_perp = out + 1048577;
    float* enc    = out + 1048578;
    float* quant  = out + 34603010;
    // scratch inside enc output region (dead until enc_k, which runs last):
    char*  encB = (char*)d_out + (size_t)1048580 * 4;
    short* h1  = (short*)encB;                       // 32 MB
    short* dt1 = h1 + 16777216;                      // 32 MB
    short* cbh  = (short*)(encB + ((size_t)120 << 20));   // 64 KB
    short* cbl  = cbh + 32768;                            // 64 KB
    float* cbsq = (float*)(cbl + 32768);                  // 2 KB
    float* errbuf = (float*)(encB + ((size_t)121 << 20)); // 4 KB

    WtArgs wa;
    wa.d[0]  = { ew2,  128,  64, 16, 0, 0      };
    wa.d[1]  = { ew3,  128, 128,  9, 0, 131072 };
    wa.d[2]  = { er1a,  32, 128,  9, 0, 278528 };
    wa.d[3]  = { er1b, 128,  32,  1, 0, 315392 };
    wa.d[4]  = { er2a,  32, 128,  9, 0, 319488 };
    wa.d[5]  = { er2b, 128,  32,  1, 0, 356352 };
    wa.d[6]  = { pw,    64, 128,  1, 0, 360448 };
    wa.d[7]  = { dw1w, 128,  64,  9, 0, 368640 };
    wa.d[8]  = { dr1a,  32, 128,  9, 0, 442368 };
    wa.d[9]  = { dr1b, 128,  32,  1, 0, 479232 };
    wa.d[10] = { dr2a,  32, 128,  9, 0, 483328 };
    wa.d[11] = { dr2b, 128,  32,  1, 0, 520192 };
    wa.d[12] = { dtw1,  64, 128, 16, 1, 524288 };
    wa.total = 655360;
    wtall_k<<<dim3(2560), TPB, 0, stream>>>(wa, wbase);
    cbprep_k<<<dim3(2), TPB, 0, stream>>>(cb, cbh, cbl, cbsq);

    // ---- encoder ----
    conv1_k<<<dim3(128, 16), TPB, 0, stream>>>(x, ew1, eb1, h1);
    pconv2_k<<<dim3(64, 16), TPB, 0, stream>>>(h1, wt2, eb2, h2);
    pconv3_k<128,128,false,false,false><<<dim3(32,16), TPB, 0, stream>>>(h2,  wt3,  eb3, buf);
    pconv3_k<128, 32,true ,true ,false><<<dim3(32,16), TPB, 0, stream>>>(buf, wr1a, nullptr, mid);
    pconv1_k< 32,128,false,false,true ,false><<<dim3(512), TPB, 0, stream>>>(mid, wr1b, nullptr, buf, buf);
    pconv3_k<128, 32,true ,true ,false><<<dim3(32,16), TPB, 0, stream>>>(buf, wr2a, nullptr, mid);
    pconv1_k< 32,128,false,false,true ,false><<<dim3(512), TPB, 0, stream>>>(mid, wr2b, nullptr, buf, buf);
    pconv1_k<128, 64,true ,false,false,true ><<<dim3(512), TPB, 0, stream>>>(buf, wpwt, pb, nullptr, z);

    // ---- VQ ----
    vqm_k<<<dim3(1024), TPB, 0, stream>>>(z, cbh, cbl, cbsq, cb, quant, qb, idx, errbuf);
    fin_k<<<dim3(1), 1024, 0, stream>>>(idx, errbuf, o_loss, o_perp);

    // ---- decoder ----
    pconv3_k< 64,128,false,false,false><<<dim3(32,16), TPB, 0, stream>>>(qb,  wd1,   db1, buf);
    pconv3_k<128, 32,true ,true ,false><<<dim3(32,16), TPB, 0, stream>>>(buf, wdr1a, nullptr, mid);
    pconv1_k< 32,128,false,false,true ,false><<<dim3(512), TPB, 0, stream>>>(mid, wdr1b, nullptr, buf, buf);
    pconv3_k<128, 32,true ,true ,false><<<dim3(32,16), TPB, 0, stream>>>(buf, wdr2a, nullptr, mid);
    pconv1_k< 32,128,false,false,true ,false><<<dim3(512), TPB, 0, stream>>>(mid, wdr2b, nullptr, buf, buf);
    pct1_k<<<dim3(128, 16), TPB, 0, stream>>>(buf, wtt1, dtb1, dt1);
    convt2_k<<<dim3(4096), TPB, 0, stream>>>(dt1, dtw2, dtb2, xrec);

    // ---- encodings (last) ----
    enc_k<<<dim3(32768), TPB, 0, stream>>>(idx, (float4*)enc);
}

// Round 7
// 605.882 us; speedup vs baseline: 1.4715x; 1.0681x over previous
//
#include <hip/hip_runtime.h>

#define TPB 256

typedef __attribute__((ext_vector_type(8))) short s8v;
typedef __attribute__((ext_vector_type(4))) float f4v;
typedef __bf16 bf16x8v __attribute__((ext_vector_type(8)));

__device__ inline short f2b(float f) {
    unsigned u = __builtin_bit_cast(unsigned, f);
    unsigned r = (u + 0x7FFF + ((u >> 16) & 1)) >> 16;
    return (short)r;
}
__device__ inline float b2f(short s) {
    unsigned u = ((unsigned)(unsigned short)s) << 16;
    return __builtin_bit_cast(float, u);
}
__device__ inline f4v mfma16(s8v a, s8v b, f4v c) {
    return __builtin_amdgcn_mfma_f32_16x16x32_bf16(
        __builtin_bit_cast(bf16x8v, a), __builtin_bit_cast(bf16x8v, b), c, 0, 0, 0);
}

// ---------------------------------------------------------------------------
// Weight prep: OIHW/IOHW fp32 -> MFMA-fragment-packed bf16:
// dst[((tap*KC+kc)*NT + nt)*512 + lane*8 + j] = W[nt*16+rl][kc*32+qd*8+j] @tap
// ---------------------------------------------------------------------------
struct WtDesc { const float* src; int CO, CI, T, iohw, start; };
struct WtArgs { WtDesc d[13]; int total; };

__global__ __launch_bounds__(256)
void wtall_k(WtArgs a, short* dst)
{
    int i = blockIdx.x * 256 + threadIdx.x;
    if (i >= a.total) return;
    int s = 0;
    for (int j = 1; j < 13; ++j) if (i >= a.d[j].start) s = j;
    int off = i - a.d[s].start;
    int CI = a.d[s].CI, CO = a.d[s].CO, T = a.d[s].T;
    int KC = CI >> 5, NT = CO >> 4;
    int j    = off & 7;
    int lane = (off >> 3) & 63;
    int rl = lane & 15, qd = lane >> 4;
    int blk = off >> 9;
    int nt  = blk % NT;
    int rest = blk / NT;
    int kc  = rest % KC;
    int tap = rest / KC;
    int co = nt * 16 + rl;
    int ci = kc * 32 + qd * 8 + j;
    float v = a.d[s].iohw ? a.d[s].src[(ci * CO + co) * T + tap]
                          : a.d[s].src[(co * CI + ci) * T + tap];
    dst[i] = f2b(v);
}

// Codebook prep: fragment-packed hi/lo bf16 + |c|^2 fp32.
__global__ __launch_bounds__(256)
void cbprep_k(const float* __restrict__ cb, short* __restrict__ cbh,
              short* __restrict__ cbl, float* __restrict__ cbsq)
{
    int c = blockIdx.x * 256 + threadIdx.x;   // 0..511
    const float* src = cb + (size_t)c * 64;
    const int nt = c >> 4, rl = c & 15;
    float sq = 0.f;
    for (int d = 0; d < 64; ++d) {
        float v = src[d];
        sq += v * v;
        short h = f2b(v);
        short lo = f2b(v - b2f(h));
        int kc = d >> 5, qd = (d >> 3) & 3, j = d & 7;
        int pos = ((kc * 32 + nt) << 9) + ((qd * 16 + rl) << 3) + j;
        cbh[pos] = h;
        cbl[pos] = lo;
    }
    cbsq[c] = sq;
}

// ---------------------------------------------------------------------------
// conv1: x (16,1,256,256) fp32 -> h1 NHWC bf16 (16,128,128,64), k4 s2 p1.
// ---------------------------------------------------------------------------
__global__ __launch_bounds__(256)
void conv1_k(const float* __restrict__ x, const float* __restrict__ w,
             const float* __restrict__ bias, short* __restrict__ out)
{
    __shared__ float sx[4 * 256];
    const int tid = threadIdx.x;
    const int oh = blockIdx.x, n = blockIdx.y;
    const int co = tid & 63, wv = tid >> 6;

    float wr[16];
#pragma unroll
    for (int t = 0; t < 16; ++t) wr[t] = w[co * 16 + t];
    const float b = bias[co];

    const float* xp = x + (size_t)n * 65536;
    for (int e = tid; e < 1024; e += 256) {
        int kh = e >> 8, col = e & 255;
        int ih = oh * 2 - 1 + kh;
        sx[e] = ((unsigned)ih < 256u) ? xp[ih * 256 + col] : 0.f;
    }
    __syncthreads();

    short* op = out + (((size_t)n * 128 + oh) * 128) * 64 + co;
#pragma unroll 4
    for (int i = 0; i < 32; ++i) {
        int ow = wv * 32 + i;
        int iwb = ow * 2 - 1;
        float acc = b;
#pragma unroll
        for (int kh = 0; kh < 4; ++kh) {
#pragma unroll
            for (int kw = 0; kw < 4; ++kw) {
                int iw = iwb + kw;
                float v = ((unsigned)iw < 256u) ? sx[kh * 256 + iw] : 0.f;
                acc = fmaf(v, wr[kh * 4 + kw], acc);
            }
        }
        op[(size_t)ow * 64] = f2b(fmaxf(acc, 0.f));
    }
}

// ---------------------------------------------------------------------------
// 3x3 s1 p1 MFMA conv, halo-LDS A + packed-B direct from global.
// ---------------------------------------------------------------------------
template<int CI, int CO, bool RELU_IN, bool RELU_OUT, bool OUT_F32>
__global__ __launch_bounds__(256)
void pconv3_k(const short* __restrict__ in, const short* __restrict__ wt,
              const float* __restrict__ bias, void* __restrict__ outv)
{
    constexpr int KC = CI / 32, NT = CO / 16;
    constexpr int NT2 = (NT >= 2) ? NT / 2 : 1;
    __shared__ short sA[4 * 68 * 40];

    const int tid = threadIdx.x;
    const int oh0 = blockIdx.x * 2;
    const int n   = blockIdx.y;
    const short* inb = in + (size_t)n * 4096 * CI;
    const int w = tid >> 6, l = tid & 63, rl = l & 15, qd = l >> 4;
    const int mh = w & 1, nh = w >> 1;

    f4v acc[4][NT2];
#pragma unroll
    for (int a4 = 0; a4 < 4; ++a4)
#pragma unroll
        for (int nt = 0; nt < NT2; ++nt) acc[a4][nt] = (f4v)0.f;

    for (int kc = 0; kc < KC; ++kc) {
        __syncthreads();
        for (int e = tid; e < 1056; e += 256) {
            int cell = e >> 2, kcn = e & 3;
            int row = cell / 66, col = cell - row * 66;
            int ih = oh0 - 1 + row, iw = col - 1;
            s8v v = (s8v)0;
            if ((unsigned)ih < 64u && (unsigned)iw < 64u) {
                v = *(const s8v*)(inb + ((size_t)ih * 64 + iw) * CI + kc * 32 + kcn * 8);
                if (RELU_IN) {
#pragma unroll
                    for (int j = 0; j < 8; ++j) if (v[j] < (short)0) v[j] = 0;
                }
            }
            *(s8v*)&sA[(row * 68 + col) * 40 + kcn * 8] = v;
        }
        __syncthreads();

#pragma unroll
        for (int tap = 0; tap < 9; ++tap) {
            const int kh = tap / 3, kw = tap % 3;
            s8v af[4];
#pragma unroll
            for (int a4 = 0; a4 < 4; ++a4)
                af[a4] = *(const s8v*)&sA[((mh + kh) * 68 + a4 * 16 + rl + kw) * 40 + qd * 8];
            const short* wb = wt + (((size_t)(tap * KC + kc) * NT + nh * NT2) << 9) + l * 8;
#pragma unroll
            for (int nt = 0; nt < NT2; ++nt) {
                s8v b = *(const s8v*)(wb + ((size_t)nt << 9));
#pragma unroll
                for (int a4 = 0; a4 < 4; ++a4)
                    acc[a4][nt] = mfma16(af[a4], b, acc[a4][nt]);
            }
        }
    }

#pragma unroll
    for (int a4 = 0; a4 < 4; ++a4) {
#pragma unroll
        for (int rg = 0; rg < 4; ++rg) {
            int ow = a4 * 16 + qd * 4 + rg;
            size_t row = (size_t)n * 4096 + (size_t)(oh0 + mh) * 64 + ow;
#pragma unroll
            for (int nt = 0; nt < NT2; ++nt) {
                int co = nh * NT2 * 16 + nt * 16 + rl;
                float v = acc[a4][nt][rg];
                if (bias) v += bias[co];
                if (RELU_OUT) v = fmaxf(v, 0.f);
                if (OUT_F32) ((float*)outv)[row * CO + co] = v;
                else         ((short*)outv)[row * CO + co] = f2b(v);
            }
        }
    }
}

// ---------------------------------------------------------------------------
// Fused resblock: out = in + conv1x1(relu(conv3x3(relu(in)))).
// 128 -> 32 -> 128, no biases. mid tile lives in LDS (no HBM round-trip).
// Phase1: 4-way M wave split (2 A-reads : 4 MFMAs). Phase3: single-K GEMM.
// in != out (ping-pong buffers).
// ---------------------------------------------------------------------------
__global__ __launch_bounds__(256)
void rfuse_k(const short* __restrict__ in, const short* __restrict__ wa,
             const short* __restrict__ wb, short* __restrict__ out)
{
    __shared__ short sA[4 * 68 * 40];     // halo; aliased as sMid after phase 1
    short* sMid = sA;                     // [m(128)][co(32)] stride 40

    const int tid = threadIdx.x;
    const int oh0 = blockIdx.x * 2;
    const int n   = blockIdx.y;
    const short* inb = in + (size_t)n * 4096 * 128;
    const int w = tid >> 6, l = tid & 63, rl = l & 15, qd = l >> 4;
    const int mh2 = w >> 1, mq = w & 1;   // phase-1: which oh row / 32-col half

    // ---- phase 1: 3x3, 128 -> 32 (relu on input at staging) ----
    f4v acc1[2][2];
#pragma unroll
    for (int a2 = 0; a2 < 2; ++a2)
#pragma unroll
        for (int nt = 0; nt < 2; ++nt) acc1[a2][nt] = (f4v)0.f;

    for (int kc = 0; kc < 4; ++kc) {
        __syncthreads();
        for (int e = tid; e < 1056; e += 256) {
            int cell = e >> 2, kcn = e & 3;
            int row = cell / 66, col = cell - row * 66;
            int ih = oh0 - 1 + row, iw = col - 1;
            s8v v = (s8v)0;
            if ((unsigned)ih < 64u && (unsigned)iw < 64u) {
                v = *(const s8v*)(inb + ((size_t)ih * 64 + iw) * 128 + kc * 32 + kcn * 8);
#pragma unroll
                for (int j = 0; j < 8; ++j) if (v[j] < (short)0) v[j] = 0;
            }
            *(s8v*)&sA[(row * 68 + col) * 40 + kcn * 8] = v;
        }
        __syncthreads();

#pragma unroll
        for (int tap = 0; tap < 9; ++tap) {
            const int kh = tap / 3, kw = tap % 3;
            s8v af[2];
#pragma unroll
            for (int a2 = 0; a2 < 2; ++a2)
                af[a2] = *(const s8v*)&sA[((mh2 + kh) * 68 + mq * 32 + a2 * 16 + rl + kw) * 40 + qd * 8];
            const short* wp = wa + (((size_t)(tap * 4 + kc) * 2) << 9) + l * 8;
#pragma unroll
            for (int nt = 0; nt < 2; ++nt) {
                s8v b = *(const s8v*)(wp + ((size_t)nt << 9));
#pragma unroll
                for (int a2 = 0; a2 < 2; ++a2)
                    acc1[a2][nt] = mfma16(af[a2], b, acc1[a2][nt]);
            }
        }
    }

    // ---- phase 2: relu(mid) -> LDS as A-layout for the 1x1 ----
    __syncthreads();
#pragma unroll
    for (int a2 = 0; a2 < 2; ++a2)
#pragma unroll
        for (int nt = 0; nt < 2; ++nt)
#pragma unroll
            for (int rg = 0; rg < 4; ++rg) {
                int m  = w * 32 + a2 * 16 + qd * 4 + rg;
                int co = nt * 16 + rl;
                sMid[m * 40 + co] = f2b(fmaxf(acc1[a2][nt][rg], 0.f));
            }
    __syncthreads();

    // ---- phase 3: 1x1, 32 -> 128 (K=32, single MFMA-K) ----
    f4v acc2[2][8];
#pragma unroll
    for (int a2 = 0; a2 < 2; ++a2)
#pragma unroll
        for (int nt = 0; nt < 8; ++nt) acc2[a2][nt] = (f4v)0.f;

    s8v am[2];
#pragma unroll
    for (int a2 = 0; a2 < 2; ++a2)
        am[a2] = *(const s8v*)&sMid[(w * 32 + a2 * 16 + rl) * 40 + qd * 8];
#pragma unroll
    for (int nt = 0; nt < 8; ++nt) {
        s8v b = *(const s8v*)(wb + ((size_t)nt << 9) + l * 8);
#pragma unroll
        for (int a2 = 0; a2 < 2; ++a2)
            acc2[a2][nt] = mfma16(am[a2], b, acc2[a2][nt]);
    }

    // ---- phase 4: residual add (re-read in, L2-hot), store ----
    short* outb = out + (size_t)n * 4096 * 128;
    const size_t sp0 = (size_t)oh0 * 64;
#pragma unroll
    for (int a2 = 0; a2 < 2; ++a2) {
#pragma unroll
        for (int rg = 0; rg < 4; ++rg) {
            int m = w * 32 + a2 * 16 + qd * 4 + rg;
            size_t sp = sp0 + m;          // m in [0,128): covers 2 rows of 64
#pragma unroll
            for (int nt = 0; nt < 8; ++nt) {
                int co = nt * 16 + rl;
                float v = acc2[a2][nt][rg] + b2f(inb[sp * 128 + co]);
                outb[sp * 128 + co] = f2b(v);
            }
        }
    }
}

// ---------------------------------------------------------------------------
// 1x1 MFMA conv (pure GEMM). Block: M=128 rows, N=CO.
// ---------------------------------------------------------------------------
template<int CI, int CO, bool RELU_IN, bool RELU_OUT, bool RES, bool OUT_F32>
__global__ __launch_bounds__(256)
void pconv1_k(const short* __restrict__ in, const short* __restrict__ wt,
              const float* __restrict__ bias, const short* __restrict__ res,
              void* __restrict__ outv)
{
    constexpr int KC = CI / 32, NT = CO / 16;
    constexpr int NT2 = (NT >= 2) ? NT / 2 : 1;
    __shared__ short sA[128 * 40];

    const int tid = threadIdx.x;
    const size_t r0 = (size_t)blockIdx.x * 128;
    const int w = tid >> 6, l = tid & 63, rl = l & 15, qd = l >> 4;
    const int mh = w & 1, nh = w >> 1;

    f4v acc[4][NT2];
#pragma unroll
    for (int a4 = 0; a4 < 4; ++a4)
#pragma unroll
        for (int nt = 0; nt < NT2; ++nt) acc[a4][nt] = (f4v)0.f;

    for (int kc = 0; kc < KC; ++kc) {
        __syncthreads();
        for (int e = tid; e < 512; e += 256) {
            int row = e >> 2, kcn = e & 3;
            s8v v = *(const s8v*)(in + (r0 + row) * CI + kc * 32 + kcn * 8);
            if (RELU_IN) {
#pragma unroll
                for (int j = 0; j < 8; ++j) if (v[j] < (short)0) v[j] = 0;
            }
            *(s8v*)&sA[row * 40 + kcn * 8] = v;
        }
        __syncthreads();

        s8v af[4];
#pragma unroll
        for (int a4 = 0; a4 < 4; ++a4)
            af[a4] = *(const s8v*)&sA[(mh * 64 + a4 * 16 + rl) * 40 + qd * 8];
        const short* wb = wt + (((size_t)kc * NT + nh * NT2) << 9) + l * 8;
#pragma unroll
        for (int nt = 0; nt < NT2; ++nt) {
            s8v b = *(const s8v*)(wb + ((size_t)nt << 9));
#pragma unroll
            for (int a4 = 0; a4 < 4; ++a4)
                acc[a4][nt] = mfma16(af[a4], b, acc[a4][nt]);
        }
    }

#pragma unroll
    for (int a4 = 0; a4 < 4; ++a4) {
#pragma unroll
        for (int rg = 0; rg < 4; ++rg) {
            size_t row = r0 + mh * 64 + a4 * 16 + qd * 4 + rg;
#pragma unroll
            for (int nt = 0; nt < NT2; ++nt) {
                int co = nh * NT2 * 16 + nt * 16 + rl;
                float v = acc[a4][nt][rg];
                if (bias) v += bias[co];
                if (RES) v += b2f(res[row * CO + co]);
                if (RELU_OUT) v = fmaxf(v, 0.f);
                if (OUT_F32) ((float*)outv)[row * CO + co] = v;
                else         ((short*)outv)[row * CO + co] = f2b(v);
            }
        }
    }
}

// ---------------------------------------------------------------------------
// conv2: k4 s2 p1, 64 -> 128. Parity-split halo. Block M=64 (1 oh row).
// ---------------------------------------------------------------------------
__global__ __launch_bounds__(256)
void pconv2_k(const short* __restrict__ in, const short* __restrict__ wt,
              const float* __restrict__ bias, short* __restrict__ out)
{
    __shared__ short sA[2 * 4 * 66 * 40];
    const int tid = threadIdx.x;
    const int oh = blockIdx.x, n = blockIdx.y;
    const short* inb = in + (size_t)n * 16384 * 64;
    const int w = tid >> 6, l = tid & 63, rl = l & 15, qd = l >> 4;
    const int mh = w & 1, nh = w >> 1;

    f4v acc[2][4];
#pragma unroll
    for (int a2 = 0; a2 < 2; ++a2)
#pragma unroll
        for (int nt = 0; nt < 4; ++nt) acc[a2][nt] = (f4v)0.f;

    for (int kc = 0; kc < 2; ++kc) {
        __syncthreads();
        for (int e = tid; e < 2112; e += 256) {
            int cell = e >> 2, kcn = e & 3;
            int par = cell / 264;
            int rem = cell - par * 264;
            int hr = rem / 66, c = rem - hr * 66;
            int iw = par ? (2 * c - 1) : (2 * c);
            int ih = oh * 2 - 1 + hr;
            s8v v = (s8v)0;
            if ((unsigned)ih < 128u && (unsigned)iw < 128u)
                v = *(const s8v*)(inb + ((size_t)ih * 128 + iw) * 64 + kc * 32 + kcn * 8);
            *(s8v*)&sA[((par * 4 + hr) * 66 + c) * 40 + kcn * 8] = v;
        }
        __syncthreads();

#pragma unroll
        for (int tap = 0; tap < 16; ++tap) {
            const int kh = tap >> 2, kw = tap & 3;
            const int par = 1 - (kw & 1), cofs = kw >> 1;
            s8v af[2];
#pragma unroll
            for (int a2 = 0; a2 < 2; ++a2) {
                int ow = mh * 32 + a2 * 16 + rl;
                af[a2] = *(const s8v*)&sA[((par * 4 + kh) * 66 + ow + cofs) * 40 + qd * 8];
            }
            const short* wb = wt + (((size_t)(tap * 2 + kc) * 8 + nh * 4) << 9) + l * 8;
#pragma unroll
            for (int nt = 0; nt < 4; ++nt) {
                s8v b = *(const s8v*)(wb + ((size_t)nt << 9));
#pragma unroll
                for (int a2 = 0; a2 < 2; ++a2)
                    acc[a2][nt] = mfma16(af[a2], b, acc[a2][nt]);
            }
        }
    }

#pragma unroll
    for (int a2 = 0; a2 < 2; ++a2) {
#pragma unroll
        for (int rg = 0; rg < 4; ++rg) {
            int ow = mh * 32 + a2 * 16 + qd * 4 + rg;
            size_t row = (size_t)n * 4096 + (size_t)oh * 64 + ow;
#pragma unroll
            for (int nt = 0; nt < 4; ++nt) {
                int co = nh * 64 + nt * 16 + rl;
                float v = acc[a2][nt][rg] + bias[co];
                out[row * 128 + co] = f2b(fmaxf(v, 0.f));
            }
        }
    }
}

// ---------------------------------------------------------------------------
// ConvT1 (k4 s2 p1, 128->64): parity conv w/ halo.
// ---------------------------------------------------------------------------
__global__ __launch_bounds__(256)
void pct1_k(const short* __restrict__ in, const short* __restrict__ wt,
            const float* __restrict__ bias, short* __restrict__ out)
{
    __shared__ short sA[3 * 66 * 40];
    const int tid = threadIdx.x;
    const int bx = blockIdx.x, n = blockIdx.y;
    const int P = bx & 1;
    const int q2 = bx >> 1;
    const int oh0 = (q2 >> 1) * 4 + (q2 & 1);
    const int p = (oh0 + 1) & 1;
    const int ihb0 = (oh0 + 1 - p) >> 1;
    const short* inb = in + (size_t)n * 4096 * 128;
    const int w = tid >> 6, l = tid & 63, rl = l & 15, qd = l >> 4;
    const int mh = w & 1, nh = w >> 1;

    f4v acc[4][2];
#pragma unroll
    for (int a4 = 0; a4 < 4; ++a4)
#pragma unroll
        for (int nt = 0; nt < 2; ++nt) acc[a4][nt] = (f4v)0.f;

    for (int kc = 0; kc < 4; ++kc) {
        __syncthreads();
        for (int e = tid; e < 792; e += 256) {
            int cell = e >> 2, kcn = e & 3;
            int hr = cell / 66, c = cell - hr * 66;
            int ih = ihb0 - 1 + hr, iw = c - 1;
            s8v v = (s8v)0;
            if ((unsigned)ih < 64u && (unsigned)iw < 64u)
                v = *(const s8v*)(inb + ((size_t)ih * 64 + iw) * 128 + kc * 32 + kcn * 8);
            *(s8v*)&sA[(hr * 66 + c) * 40 + kcn * 8] = v;
        }
        __syncthreads();

#pragma unroll
        for (int a = 0; a < 2; ++a)
#pragma unroll
        for (int b = 0; b < 2; ++b) {
            const int kh = p + 2 * a;
            const int kw = (1 - P) + 2 * b;
            const int tap = kh * 4 + kw;
            const int hrw = mh + 1 - a;
            s8v af[4];
#pragma unroll
            for (int a4 = 0; a4 < 4; ++a4)
                af[a4] = *(const s8v*)&sA[(hrw * 66 + a4 * 16 + rl + P - b + 1) * 40 + qd * 8];
            const short* wbp = wt + (((size_t)(tap * 4 + kc) * 4 + nh * 2) << 9) + l * 8;
#pragma unroll
            for (int nt = 0; nt < 2; ++nt) {
                s8v bb = *(const s8v*)(wbp + ((size_t)nt << 9));
#pragma unroll
                for (int a4 = 0; a4 < 4; ++a4)
                    acc[a4][nt] = mfma16(af[a4], bb, acc[a4][nt]);
            }
        }
    }

#pragma unroll
    for (int a4 = 0; a4 < 4; ++a4) {
#pragma unroll
        for (int rg = 0; rg < 4; ++rg) {
            int j = a4 * 16 + qd * 4 + rg;
            int oh = oh0 + 2 * mh, ow = 2 * j + P;
            size_t pb = (((size_t)n * 128 + oh) * 128 + ow) * 64;
#pragma unroll
            for (int nt = 0; nt < 2; ++nt) {
                int co = nh * 32 + nt * 16 + rl;
                float v = acc[a4][nt][rg] + bias[co];
                out[pb + co] = f2b(fmaxf(v, 0.f));
            }
        }
    }
}

// ---------------------------------------------------------------------------
// ConvT2: in NHWC bf16 (16,128,128,64) -> x_rec fp32 (16,256,256), k4 s2 p1.
// ---------------------------------------------------------------------------
__global__ __launch_bounds__(256)
void convt2_k(const short* __restrict__ in, const float* __restrict__ w,
              const float* __restrict__ bias, float* __restrict__ out)
{
    __shared__ float sw[16 * 64];
    const int tid = threadIdx.x;
    for (int e = tid; e < 1024; e += 256) { int ci = e >> 4, tap = e & 15; sw[tap * 64 + ci] = w[e]; }
    __syncthreads();

    const int i = blockIdx.x * 256 + tid;
    const int n = i >> 16, s = i & 65535;
    const int oh = s >> 8, ow = s & 255;

    const int p = (oh + 1) & 1, q = (ow + 1) & 1;
    const int ihb = (oh + 1 - p) >> 1, iwb = (ow + 1 - q) >> 1;

    float acc = bias[0];
#pragma unroll
    for (int a = 0; a < 2; ++a) {
        int ih = ihb - a, kh = p + 2 * a;
        bool vr = (unsigned)ih < 128u;
#pragma unroll
        for (int b = 0; b < 2; ++b) {
            int iw = iwb - b, kw = q + 2 * b;
            if (vr && (unsigned)iw < 128u) {
                const short* ip = in + (((size_t)n * 128 + ih) * 128 + iw) * 64;
                const float* wp = &sw[(kh * 4 + kw) * 64];
#pragma unroll
                for (int c = 0; c < 64; c += 8) {
                    s8v v = *(const s8v*)(ip + c);
#pragma unroll
                    for (int j = 0; j < 8; ++j) acc += b2f(v[j]) * wp[c + j];
                }
            }
        }
    }
    out[i] = acc;
}

// ---------------------------------------------------------------------------
// VQ: MFMA distance GEMM, split-bf16, fully-coalesced; no global atomics.
// ---------------------------------------------------------------------------
__global__ __launch_bounds__(256)
void vqm_k(const float* __restrict__ z, const short* __restrict__ cbh,
           const short* __restrict__ cbl, const float* __restrict__ cbsq,
           const float* __restrict__ cb,
           float* __restrict__ quant, short* __restrict__ qb,
           int* __restrict__ idxp, float* __restrict__ errbuf)
{
    __shared__ float zs[64 * 68];
    __shared__ short scb[2][8192];
    __shared__ int sidx[64];
    __shared__ float serr[4];
    float* qc = (float*)&scb[0][0];

    const int tid = threadIdx.x;
    const int w = tid >> 6, l = tid & 63, rl = l & 15, qd = l >> 4;
    const int r0 = blockIdx.x * 64;

    for (int e = tid; e < 1024; e += 256) {
        int row = e >> 4, c4 = e & 15;
        float4 t = ((const float4*)(z + (size_t)(r0 + row) * 64))[c4];
        *(float4*)&zs[row * 68 + c4 * 4] = t;
    }
    __syncthreads();

    s8v zh[2], zl[2];
#pragma unroll
    for (int kc = 0; kc < 2; ++kc) {
        const float* zp = &zs[(w * 16 + rl) * 68 + kc * 32 + qd * 8];
        s8v hi, lo;
#pragma unroll
        for (int j = 0; j < 8; ++j) {
            float v = zp[j];
            short h = f2b(v);
            hi[j] = h;
            lo[j] = f2b(v - b2f(h));
        }
        zh[kc] = hi; zl[kc] = lo;
    }

    float best[4]; int bidx[4];
#pragma unroll
    for (int rg = 0; rg < 4; ++rg) { best[rg] = 3.4e38f; bidx[rg] = 0; }

    for (int ch = 0; ch < 4; ++ch) {
        __syncthreads();
        for (int e = tid; e < 1024; e += 256) {
            int kcL = e >> 9, rest = e & 511;
            int ntl = rest >> 6, off = rest & 63;
            int srcIdx = (kcL * 32 + ch * 8 + ntl) * 64 + off;
            *(s8v*)&scb[0][e * 8] = ((const s8v*)cbh)[srcIdx];
            *(s8v*)&scb[1][e * 8] = ((const s8v*)cbl)[srcIdx];
        }
        __syncthreads();

        float sq[8];
#pragma unroll
        for (int nt = 0; nt < 8; ++nt) sq[nt] = cbsq[ch * 128 + nt * 16 + rl];

        f4v acc[8];
#pragma unroll
        for (int nt = 0; nt < 8; ++nt) acc[nt] = (f4v)0.f;
#pragma unroll
        for (int kc = 0; kc < 2; ++kc) {
#pragma unroll
            for (int nt = 0; nt < 8; ++nt) {
                s8v bh = *(const s8v*)&scb[0][(kc * 8 + nt) * 512 + l * 8];
                s8v bl = *(const s8v*)&scb[1][(kc * 8 + nt) * 512 + l * 8];
                acc[nt] = mfma16(zh[kc], bh, acc[nt]);
                acc[nt] = mfma16(zh[kc], bl, acc[nt]);
                acc[nt] = mfma16(zl[kc], bh, acc[nt]);
            }
        }

#pragma unroll
        for (int rg = 0; rg < 4; ++rg) {
            float bd = best[rg]; int bi = bidx[rg];
#pragma unroll
            for (int nt = 0; nt < 8; ++nt) {
                float d = sq[nt] - 2.f * acc[nt][rg];
                int code = ch * 128 + nt * 16 + rl;
                if (d < bd) { bd = d; bi = code; }
            }
            best[rg] = bd; bidx[rg] = bi;
        }
    }

#pragma unroll
    for (int rg = 0; rg < 4; ++rg) {
        float bd = best[rg]; int bi = bidx[rg];
#pragma unroll
        for (int off = 1; off < 16; off <<= 1) {
            float od = __shfl_xor(bd, off, 64);
            int   oi = __shfl_xor(bi, off, 64);
            if (od < bd || (od == bd && oi < bi)) { bd = od; bi = oi; }
        }
        if (rl == 0) sidx[w * 16 + qd * 4 + rg] = bi;
    }
    __syncthreads();

    const int n = r0 >> 12, s0 = r0 & 4095;
    float err = 0.f;
#pragma unroll 4
    for (int i = 0; i < 16; ++i) {
        int rr = w * 16 + i;
        int bi = sidx[rr];
        float c = cb[(size_t)bi * 64 + l];
        float zv = zs[rr * 68 + l];
        float dd = zv - c;
        err += dd * dd;
        qb[(size_t)(r0 + rr) * 64 + l] = f2b(c);
        qc[l * 68 + rr] = c;
    }
#pragma unroll
    for (int o = 32; o; o >>= 1) err += __shfl_down(err, o, 64);
    if (l == 0) serr[w] = err;
    if (tid < 64) idxp[r0 + tid] = sidx[tid];
    __syncthreads();

#pragma unroll 4
    for (int dd = 0; dd < 16; ++dd) {
        int d = w * 16 + dd;
        quant[((size_t)(n * 64 + d)) * 4096 + s0 + l] = qc[d * 68 + l];
    }
    if (tid == 0) errbuf[blockIdx.x] = serr[0] + serr[1] + serr[2] + serr[3];
}

__global__ __launch_bounds__(1024)
void fin_k(const int* __restrict__ idxp, const float* __restrict__ errbuf,
           float* out_loss, float* out_perp)
{
    __shared__ int lc[512];
    __shared__ float red[1024];
    const int t = threadIdx.x;
    if (t < 512) lc[t] = 0;
    __syncthreads();
    for (int i = t; i < 65536; i += 1024) atomicAdd(&lc[idxp[i]], 1);
    __syncthreads();
    float v = 0.f;
    if (t < 512) {
        float avg = (float)lc[t] * (1.0f / 65536.0f);
        v = avg * logf(avg + 1e-10f);
    }
    red[t] = v;
    __syncthreads();
    for (int st = 512; st; st >>= 1) { if (t < st) red[t] += red[t + st]; __syncthreads(); }
    if (t == 0) *out_perp = expf(-red[0]);
    __syncthreads();
    red[t] = errbuf[t];
    __syncthreads();
    for (int st = 512; st; st >>= 1) { if (t < st) red[t] += red[t + st]; __syncthreads(); }
    if (t == 0) *out_loss = red[0] * (1.25f / 4194304.0f);
}

__global__ __launch_bounds__(256)
void enc_k(const int* __restrict__ idxp, float4* __restrict__ enc)
{
    int i = blockIdx.x * 256 + threadIdx.x;
    int r = i >> 7, c4 = (i & 127) * 4;
    int k = idxp[r];
    float4 v;
    v.x = (k == c4)     ? 1.f : 0.f;
    v.y = (k == c4 + 1) ? 1.f : 0.f;
    v.z = (k == c4 + 2) ? 1.f : 0.f;
    v.w = (k == c4 + 3) ? 1.f : 0.f;
    enc[i] = v;
}

// ---------------------------------------------------------------------------
extern "C" void kernel_launch(void* const* d_in, const int* in_sizes, int n_in,
                              void* d_out, int out_size, void* d_ws, size_t ws_size,
                              hipStream_t stream)
{
    const float* x    = (const float*)d_in[0];
    const float* ew1  = (const float*)d_in[1];
    const float* eb1  = (const float*)d_in[2];
    const float* ew2  = (const float*)d_in[3];
    const float* eb2  = (const float*)d_in[4];
    const float* ew3  = (const float*)d_in[5];
    const float* eb3  = (const float*)d_in[6];
    const float* er1a = (const float*)d_in[7];
    const float* er1b = (const float*)d_in[8];
    const float* er2a = (const float*)d_in[9];
    const float* er2b = (const float*)d_in[10];
    const float* pw   = (const float*)d_in[11];
    const float* pb   = (const float*)d_in[12];
    const float* cb   = (const float*)d_in[13];
    const float* dw1w = (const float*)d_in[14];
    const float* db1  = (const float*)d_in[15];
    const float* dr1a = (const float*)d_in[16];
    const float* dr1b = (const float*)d_in[17];
    const float* dr2a = (const float*)d_in[18];
    const float* dr2b = (const float*)d_in[19];
    const float* dtw1 = (const float*)d_in[20];
    const float* dtb1 = (const float*)d_in[21];
    const float* dtw2 = (const float*)d_in[22];
    const float* dtb2 = (const float*)d_in[23];

    char* wsb = (char*)d_ws;
    short* wbase = (short*)wsb;
    short* wt2   = wbase;
    short* wt3   = wbase + 131072;
    short* wr1a  = wbase + 278528;
    short* wr1b  = wbase + 315392;
    short* wr2a  = wbase + 319488;
    short* wr2b  = wbase + 356352;
    short* wpwt  = wbase + 360448;
    short* wd1   = wbase + 368640;
    short* wdr1a = wbase + 442368;
    short* wdr1b = wbase + 479232;
    short* wdr2a = wbase + 483328;
    short* wdr2b = wbase + 520192;
    short* wtt1  = wbase + 524288;

    short* h2   = (short*)(wsb + 1310720);
    short* buf  = (short*)(wsb + 18087936);
    short* qb   = (short*)(wsb + 39059456);
    float* z    = (float*)(wsb + 47448064);
    int*   idx  = (int*)  (wsb + 64225280);
    if (ws_size < (size_t)64489480) return;

    float* out    = (float*)d_out;
    float* o_loss = out;
    float* xrec   = out + 1;
    float* o_perp = out + 1048577;
    float* enc    = out + 1048578;
    float* quant  = out + 34603010;
    char*  encB = (char*)d_out + (size_t)1048580 * 4;
    short* h1  = (short*)encB;
    short* dt1 = h1 + 16777216;
    short* cbh  = (short*)(encB + ((size_t)120 << 20));
    short* cbl  = cbh + 32768;
    float* cbsq = (float*)(cbl + 32768);
    float* errbuf = (float*)(encB + ((size_t)121 << 20));

    WtArgs wa;
    wa.d[0]  = { ew2,  128,  64, 16, 0, 0      };
    wa.d[1]  = { ew3,  128, 128,  9, 0, 131072 };
    wa.d[2]  = { er1a,  32, 128,  9, 0, 278528 };
    wa.d[3]  = { er1b, 128,  32,  1, 0, 315392 };
    wa.d[4]  = { er2a,  32, 128,  9, 0, 319488 };
    wa.d[5]  = { er2b, 128,  32,  1, 0, 356352 };
    wa.d[6]  = { pw,    64, 128,  1, 0, 360448 };
    wa.d[7]  = { dw1w, 128,  64,  9, 0, 368640 };
    wa.d[8]  = { dr1a,  32, 128,  9, 0, 442368 };
    wa.d[9]  = { dr1b, 128,  32,  1, 0, 479232 };
    wa.d[10] = { dr2a,  32, 128,  9, 0, 483328 };
    wa.d[11] = { dr2b, 128,  32,  1, 0, 520192 };
    wa.d[12] = { dtw1,  64, 128, 16, 1, 524288 };
    wa.total = 655360;
    wtall_k<<<dim3(2560), TPB, 0, stream>>>(wa, wbase);
    cbprep_k<<<dim3(2), TPB, 0, stream>>>(cb, cbh, cbl, cbsq);

    // ---- encoder ----
    conv1_k<<<dim3(128, 16), TPB, 0, stream>>>(x, ew1, eb1, h1);
    pconv2_k<<<dim3(64, 16), TPB, 0, stream>>>(h1, wt2, eb2, h2);
    pconv3_k<128,128,false,false,false><<<dim3(32,16), TPB, 0, stream>>>(h2, wt3, eb3, buf);
    rfuse_k<<<dim3(32,16), TPB, 0, stream>>>(buf, wr1a, wr1b, h2);   // res1: buf -> h2
    rfuse_k<<<dim3(32,16), TPB, 0, stream>>>(h2,  wr2a, wr2b, buf);  // res2: h2 -> buf
    pconv1_k<128, 64,true ,false,false,true ><<<dim3(512), TPB, 0, stream>>>(buf, wpwt, pb, nullptr, z);

    // ---- VQ ----
    vqm_k<<<dim3(1024), TPB, 0, stream>>>(z, cbh, cbl, cbsq, cb, quant, qb, idx, errbuf);
    fin_k<<<dim3(1), 1024, 0, stream>>>(idx, errbuf, o_loss, o_perp);

    // ---- decoder ----
    pconv3_k< 64,128,false,false,false><<<dim3(32,16), TPB, 0, stream>>>(qb, wd1, db1, buf);
    rfuse_k<<<dim3(32,16), TPB, 0, stream>>>(buf, wdr1a, wdr1b, h2);  // dres1: buf -> h2
    rfuse_k<<<dim3(32,16), TPB, 0, stream>>>(h2,  wdr2a, wdr2b, buf); // dres2: h2 -> buf
    pct1_k<<<dim3(128, 16), TPB, 0, stream>>>(buf, wtt1, dtb1, dt1);
    convt2_k<<<dim3(4096), TPB, 0, stream>>>(dt1, dtw2, dtb2, xrec);

    // ---- encodings (last) ----
    enc_k<<<dim3(32768), TPB, 0, stream>>>(idx, (float4*)enc);
}

// Round 8
// 600.525 us; speedup vs baseline: 1.4846x; 1.0089x over previous
//
#include <hip/hip_runtime.h>

#define TPB 256

typedef __attribute__((ext_vector_type(8))) short s8v;
typedef __attribute__((ext_vector_type(4))) float f4v;
typedef __bf16 bf16x8v __attribute__((ext_vector_type(8)));

__device__ inline short f2b(float f) {
    unsigned u = __builtin_bit_cast(unsigned, f);
    unsigned r = (u + 0x7FFF + ((u >> 16) & 1)) >> 16;
    return (short)r;
}
__device__ inline float b2f(short s) {
    unsigned u = ((unsigned)(unsigned short)s) << 16;
    return __builtin_bit_cast(float, u);
}
__device__ inline f4v mfma16(s8v a, s8v b, f4v c) {
    return __builtin_amdgcn_mfma_f32_16x16x32_bf16(
        __builtin_bit_cast(bf16x8v, a), __builtin_bit_cast(bf16x8v, b), c, 0, 0, 0);
}

// ---------------------------------------------------------------------------
// Weight prep: OIHW/IOHW fp32 -> MFMA-fragment-packed bf16:
// dst[((tap*KC+kc)*NT + nt)*512 + lane*8 + j] = W[nt*16+rl][kc*32+qd*8+j] @tap
// ---------------------------------------------------------------------------
struct WtDesc { const float* src; int CO, CI, T, iohw, start; };
struct WtArgs { WtDesc d[13]; int total; };

__global__ __launch_bounds__(256)
void wtall_k(WtArgs a, short* dst)
{
    int i = blockIdx.x * 256 + threadIdx.x;
    if (i >= a.total) return;
    int s = 0;
    for (int j = 1; j < 13; ++j) if (i >= a.d[j].start) s = j;
    int off = i - a.d[s].start;
    int CI = a.d[s].CI, CO = a.d[s].CO, T = a.d[s].T;
    int KC = CI >> 5, NT = CO >> 4;
    int j    = off & 7;
    int lane = (off >> 3) & 63;
    int rl = lane & 15, qd = lane >> 4;
    int blk = off >> 9;
    int nt  = blk % NT;
    int rest = blk / NT;
    int kc  = rest % KC;
    int tap = rest / KC;
    int co = nt * 16 + rl;
    int ci = kc * 32 + qd * 8 + j;
    float v = a.d[s].iohw ? a.d[s].src[(ci * CO + co) * T + tap]
                          : a.d[s].src[(co * CI + ci) * T + tap];
    dst[i] = f2b(v);
}

// Codebook prep: fragment-packed hi/lo bf16 + |c|^2 fp32.
__global__ __launch_bounds__(256)
void cbprep_k(const float* __restrict__ cb, short* __restrict__ cbh,
              short* __restrict__ cbl, float* __restrict__ cbsq)
{
    int c = blockIdx.x * 256 + threadIdx.x;   // 0..511
    const float* src = cb + (size_t)c * 64;
    const int nt = c >> 4, rl = c & 15;
    float sq = 0.f;
    for (int d = 0; d < 64; ++d) {
        float v = src[d];
        sq += v * v;
        short h = f2b(v);
        short lo = f2b(v - b2f(h));
        int kc = d >> 5, qd = (d >> 3) & 3, j = d & 7;
        int pos = ((kc * 32 + nt) << 9) + ((qd * 16 + rl) << 3) + j;
        cbh[pos] = h;
        cbl[pos] = lo;
    }
    cbsq[c] = sq;
}

// ---------------------------------------------------------------------------
// conv1: x (16,1,256,256) fp32 -> h1 NHWC bf16 (16,128,128,64), k4 s2 p1.
// ---------------------------------------------------------------------------
__global__ __launch_bounds__(256)
void conv1_k(const float* __restrict__ x, const float* __restrict__ w,
             const float* __restrict__ bias, short* __restrict__ out)
{
    __shared__ float sx[4 * 256];
    const int tid = threadIdx.x;
    const int oh = blockIdx.x, n = blockIdx.y;
    const int co = tid & 63, wv = tid >> 6;

    float wr[16];
#pragma unroll
    for (int t = 0; t < 16; ++t) wr[t] = w[co * 16 + t];
    const float b = bias[co];

    const float* xp = x + (size_t)n * 65536;
    for (int e = tid; e < 1024; e += 256) {
        int kh = e >> 8, col = e & 255;
        int ih = oh * 2 - 1 + kh;
        sx[e] = ((unsigned)ih < 256u) ? xp[ih * 256 + col] : 0.f;
    }
    __syncthreads();

    short* op = out + (((size_t)n * 128 + oh) * 128) * 64 + co;
#pragma unroll 4
    for (int i = 0; i < 32; ++i) {
        int ow = wv * 32 + i;
        int iwb = ow * 2 - 1;
        float acc = b;
#pragma unroll
        for (int kh = 0; kh < 4; ++kh) {
#pragma unroll
            for (int kw = 0; kw < 4; ++kw) {
                int iw = iwb + kw;
                float v = ((unsigned)iw < 256u) ? sx[kh * 256 + iw] : 0.f;
                acc = fmaf(v, wr[kh * 4 + kw], acc);
            }
        }
        op[(size_t)ow * 64] = f2b(fmaxf(acc, 0.f));
    }
}

// ---------------------------------------------------------------------------
// 3x3 s1 p1 MFMA conv, M=64 (1 oh row/block) for high occupancy.
// Halo 3x66 in LDS; packed-B direct from global. Waves 2x2: M-half x CO-half.
// Grid (64, N).
// ---------------------------------------------------------------------------
template<int CI, int CO, bool RELU_IN, bool RELU_OUT, bool OUT_F32>
__global__ __launch_bounds__(256)
void pconv3s_k(const short* __restrict__ in, const short* __restrict__ wt,
               const float* __restrict__ bias, void* __restrict__ outv)
{
    constexpr int KC = CI / 32, NT = CO / 16;
    constexpr int NT2 = NT / 2;
    __shared__ short sA[3 * 66 * 40];

    const int tid = threadIdx.x;
    const int oh = blockIdx.x;
    const int n  = blockIdx.y;
    const short* inb = in + (size_t)n * 4096 * CI;
    const int w = tid >> 6, l = tid & 63, rl = l & 15, qd = l >> 4;
    const int mh = w & 1, nh = w >> 1;

    f4v acc[2][NT2];
#pragma unroll
    for (int a2 = 0; a2 < 2; ++a2)
#pragma unroll
        for (int nt = 0; nt < NT2; ++nt) acc[a2][nt] = (f4v)0.f;

    for (int kc = 0; kc < KC; ++kc) {
        __syncthreads();
        for (int e = tid; e < 792; e += 256) {
            int cell = e >> 2, kcn = e & 3;
            int hr = cell / 66, col = cell - hr * 66;
            int ih = oh - 1 + hr, iw = col - 1;
            s8v v = (s8v)0;
            if ((unsigned)ih < 64u && (unsigned)iw < 64u) {
                v = *(const s8v*)(inb + ((size_t)ih * 64 + iw) * CI + kc * 32 + kcn * 8);
                if (RELU_IN) {
#pragma unroll
                    for (int j = 0; j < 8; ++j) if (v[j] < (short)0) v[j] = 0;
                }
            }
            *(s8v*)&sA[(hr * 66 + col) * 40 + kcn * 8] = v;
        }
        __syncthreads();

#pragma unroll
        for (int tap = 0; tap < 9; ++tap) {
            const int kh = tap / 3, kw = tap % 3;
            s8v af[2];
#pragma unroll
            for (int a2 = 0; a2 < 2; ++a2)
                af[a2] = *(const s8v*)&sA[(kh * 66 + mh * 32 + a2 * 16 + rl + kw) * 40 + qd * 8];
            const short* wb = wt + (((size_t)(tap * KC + kc) * NT + nh * NT2) << 9) + l * 8;
#pragma unroll
            for (int nt = 0; nt < NT2; ++nt) {
                s8v b = *(const s8v*)(wb + ((size_t)nt << 9));
#pragma unroll
                for (int a2 = 0; a2 < 2; ++a2)
                    acc[a2][nt] = mfma16(af[a2], b, acc[a2][nt]);
            }
        }
    }

#pragma unroll
    for (int a2 = 0; a2 < 2; ++a2) {
#pragma unroll
        for (int rg = 0; rg < 4; ++rg) {
            int ow = mh * 32 + a2 * 16 + qd * 4 + rg;
            size_t row = (size_t)n * 4096 + (size_t)oh * 64 + ow;
#pragma unroll
            for (int nt = 0; nt < NT2; ++nt) {
                int co = nh * NT2 * 16 + nt * 16 + rl;
                float v = acc[a2][nt][rg];
                if (bias) v += bias[co];
                if (RELU_OUT) v = fmaxf(v, 0.f);
                if (OUT_F32) ((float*)outv)[row * CO + co] = v;
                else         ((short*)outv)[row * CO + co] = f2b(v);
            }
        }
    }
}

// ---------------------------------------------------------------------------
// Fused resblock, M=64: out = in + conv1x1(relu(conv3x3(relu(in)))).
// 128 -> 32 -> 128. Grid (64, 16). LDS 15.8 KB -> high co-residency.
// ---------------------------------------------------------------------------
__global__ __launch_bounds__(256)
void rfuse_k(const short* __restrict__ in, const short* __restrict__ wa,
             const short* __restrict__ wb, short* __restrict__ out)
{
    __shared__ short sA[3 * 66 * 40];     // halo; sMid (64x40) aliases it
    short* sMid = sA;

    const int tid = threadIdx.x;
    const int oh = blockIdx.x;
    const int n  = blockIdx.y;
    const short* inb = in + (size_t)n * 4096 * 128;
    const int w = tid >> 6, l = tid & 63, rl = l & 15, qd = l >> 4;

    // ---- phase 1: 3x3, 128 -> 32 (relu at staging); wave w = 16 M-rows ----
    f4v acc1[2];
    acc1[0] = (f4v)0.f; acc1[1] = (f4v)0.f;

    for (int kc = 0; kc < 4; ++kc) {
        __syncthreads();
        for (int e = tid; e < 792; e += 256) {
            int cell = e >> 2, kcn = e & 3;
            int hr = cell / 66, col = cell - hr * 66;
            int ih = oh - 1 + hr, iw = col - 1;
            s8v v = (s8v)0;
            if ((unsigned)ih < 64u && (unsigned)iw < 64u) {
                v = *(const s8v*)(inb + ((size_t)ih * 64 + iw) * 128 + kc * 32 + kcn * 8);
#pragma unroll
                for (int j = 0; j < 8; ++j) if (v[j] < (short)0) v[j] = 0;
            }
            *(s8v*)&sA[(hr * 66 + col) * 40 + kcn * 8] = v;
        }
        __syncthreads();

#pragma unroll
        for (int tap = 0; tap < 9; ++tap) {
            const int kh = tap / 3, kw = tap % 3;
            s8v af = *(const s8v*)&sA[(kh * 66 + w * 16 + rl + kw) * 40 + qd * 8];
            const short* wp = wa + (((size_t)(tap * 4 + kc) * 2) << 9) + l * 8;
            acc1[0] = mfma16(af, *(const s8v*)(wp),       acc1[0]);
            acc1[1] = mfma16(af, *(const s8v*)(wp + 512), acc1[1]);
        }
    }

    // ---- phase 2: relu(mid) -> LDS (A-layout for the 1x1) ----
    __syncthreads();
#pragma unroll
    for (int nt = 0; nt < 2; ++nt)
#pragma unroll
        for (int rg = 0; rg < 4; ++rg) {
            int m  = w * 16 + qd * 4 + rg;
            int co = nt * 16 + rl;
            sMid[m * 40 + co] = f2b(fmaxf(acc1[nt][rg], 0.f));
        }
    __syncthreads();

    // ---- phase 3: 1x1, 32 -> 128 (K=32, single MFMA-K) ----
    f4v acc2[8];
#pragma unroll
    for (int nt = 0; nt < 8; ++nt) acc2[nt] = (f4v)0.f;

    s8v am = *(const s8v*)&sMid[(w * 16 + rl) * 40 + qd * 8];
#pragma unroll
    for (int nt = 0; nt < 8; ++nt) {
        s8v b = *(const s8v*)(wb + ((size_t)nt << 9) + l * 8);
        acc2[nt] = mfma16(am, b, acc2[nt]);
    }

    // ---- phase 4: residual add (re-read in, L2-hot), store ----
    short* outb = out + (size_t)n * 4096 * 128;
    const size_t sp0 = (size_t)oh * 64;
#pragma unroll
    for (int rg = 0; rg < 4; ++rg) {
        int m = w * 16 + qd * 4 + rg;
        size_t sp = sp0 + m;
#pragma unroll
        for (int nt = 0; nt < 8; ++nt) {
            int co = nt * 16 + rl;
            float v = acc2[nt][rg] + b2f(inb[sp * 128 + co]);
            outb[sp * 128 + co] = f2b(v);
        }
    }
}

// ---------------------------------------------------------------------------
// 1x1 MFMA conv (pure GEMM), M=64. Grid = rows/64. wave = 16 rows x full CO.
// ---------------------------------------------------------------------------
template<int CI, int CO, bool RELU_IN, bool RELU_OUT, bool OUT_F32>
__global__ __launch_bounds__(256)
void pconv1s_k(const short* __restrict__ in, const short* __restrict__ wt,
               const float* __restrict__ bias, void* __restrict__ outv)
{
    constexpr int KC = CI / 32, NT = CO / 16;
    __shared__ short sA[64 * 40];

    const int tid = threadIdx.x;
    const size_t r0 = (size_t)blockIdx.x * 64;
    const int w = tid >> 6, l = tid & 63, rl = l & 15, qd = l >> 4;

    f4v acc[NT];
#pragma unroll
    for (int nt = 0; nt < NT; ++nt) acc[nt] = (f4v)0.f;

    for (int kc = 0; kc < KC; ++kc) {
        __syncthreads();
        {
            int row = tid >> 2, kcn = tid & 3;
            s8v v = *(const s8v*)(in + (r0 + row) * CI + kc * 32 + kcn * 8);
            if (RELU_IN) {
#pragma unroll
                for (int j = 0; j < 8; ++j) if (v[j] < (short)0) v[j] = 0;
            }
            *(s8v*)&sA[row * 40 + kcn * 8] = v;
        }
        __syncthreads();

        s8v af = *(const s8v*)&sA[(w * 16 + rl) * 40 + qd * 8];
        const short* wb = wt + (((size_t)kc * NT) << 9) + l * 8;
#pragma unroll
        for (int nt = 0; nt < NT; ++nt) {
            s8v b = *(const s8v*)(wb + ((size_t)nt << 9));
            acc[nt] = mfma16(af, b, acc[nt]);
        }
    }

#pragma unroll
    for (int rg = 0; rg < 4; ++rg) {
        size_t row = r0 + w * 16 + qd * 4 + rg;
#pragma unroll
        for (int nt = 0; nt < NT; ++nt) {
            int co = nt * 16 + rl;
            float v = acc[nt][rg];
            if (bias) v += bias[co];
            if (RELU_OUT) v = fmaxf(v, 0.f);
            if (OUT_F32) ((float*)outv)[row * CO + co] = v;
            else         ((short*)outv)[row * CO + co] = f2b(v);
        }
    }
}

// ---------------------------------------------------------------------------
// conv2: k4 s2 p1, 64 -> 128. Parity-split halo. Block M=64 (1 oh row).
// ---------------------------------------------------------------------------
__global__ __launch_bounds__(256)
void pconv2_k(const short* __restrict__ in, const short* __restrict__ wt,
              const float* __restrict__ bias, short* __restrict__ out)
{
    __shared__ short sA[2 * 4 * 66 * 40];
    const int tid = threadIdx.x;
    const int oh = blockIdx.x, n = blockIdx.y;
    const short* inb = in + (size_t)n * 16384 * 64;
    const int w = tid >> 6, l = tid & 63, rl = l & 15, qd = l >> 4;
    const int mh = w & 1, nh = w >> 1;

    f4v acc[2][4];
#pragma unroll
    for (int a2 = 0; a2 < 2; ++a2)
#pragma unroll
        for (int nt = 0; nt < 4; ++nt) acc[a2][nt] = (f4v)0.f;

    for (int kc = 0; kc < 2; ++kc) {
        __syncthreads();
        for (int e = tid; e < 2112; e += 256) {
            int cell = e >> 2, kcn = e & 3;
            int par = cell / 264;
            int rem = cell - par * 264;
            int hr = rem / 66, c = rem - hr * 66;
            int iw = par ? (2 * c - 1) : (2 * c);
            int ih = oh * 2 - 1 + hr;
            s8v v = (s8v)0;
            if ((unsigned)ih < 128u && (unsigned)iw < 128u)
                v = *(const s8v*)(inb + ((size_t)ih * 128 + iw) * 64 + kc * 32 + kcn * 8);
            *(s8v*)&sA[((par * 4 + hr) * 66 + c) * 40 + kcn * 8] = v;
        }
        __syncthreads();

#pragma unroll
        for (int tap = 0; tap < 16; ++tap) {
            const int kh = tap >> 2, kw = tap & 3;
            const int par = 1 - (kw & 1), cofs = kw >> 1;
            s8v af[2];
#pragma unroll
            for (int a2 = 0; a2 < 2; ++a2) {
                int ow = mh * 32 + a2 * 16 + rl;
                af[a2] = *(const s8v*)&sA[((par * 4 + kh) * 66 + ow + cofs) * 40 + qd * 8];
            }
            const short* wb = wt + (((size_t)(tap * 2 + kc) * 8 + nh * 4) << 9) + l * 8;
#pragma unroll
            for (int nt = 0; nt < 4; ++nt) {
                s8v b = *(const s8v*)(wb + ((size_t)nt << 9));
#pragma unroll
                for (int a2 = 0; a2 < 2; ++a2)
                    acc[a2][nt] = mfma16(af[a2], b, acc[a2][nt]);
            }
        }
    }

#pragma unroll
    for (int a2 = 0; a2 < 2; ++a2) {
#pragma unroll
        for (int rg = 0; rg < 4; ++rg) {
            int ow = mh * 32 + a2 * 16 + qd * 4 + rg;
            size_t row = (size_t)n * 4096 + (size_t)oh * 64 + ow;
#pragma unroll
            for (int nt = 0; nt < 4; ++nt) {
                int co = nh * 64 + nt * 16 + rl;
                float v = acc[a2][nt][rg] + bias[co];
                out[row * 128 + co] = f2b(fmaxf(v, 0.f));
            }
        }
    }
}

// ---------------------------------------------------------------------------
// ConvT1 (k4 s2 p1, 128->64): parity conv w/ halo.
// ---------------------------------------------------------------------------
__global__ __launch_bounds__(256)
void pct1_k(const short* __restrict__ in, const short* __restrict__ wt,
            const float* __restrict__ bias, short* __restrict__ out)
{
    __shared__ short sA[3 * 66 * 40];
    const int tid = threadIdx.x;
    const int bx = blockIdx.x, n = blockIdx.y;
    const int P = bx & 1;
    const int q2 = bx >> 1;
    const int oh0 = (q2 >> 1) * 4 + (q2 & 1);
    const int p = (oh0 + 1) & 1;
    const int ihb0 = (oh0 + 1 - p) >> 1;
    const short* inb = in + (size_t)n * 4096 * 128;
    const int w = tid >> 6, l = tid & 63, rl = l & 15, qd = l >> 4;
    const int mh = w & 1, nh = w >> 1;

    f4v acc[4][2];
#pragma unroll
    for (int a4 = 0; a4 < 4; ++a4)
#pragma unroll
        for (int nt = 0; nt < 2; ++nt) acc[a4][nt] = (f4v)0.f;

    for (int kc = 0; kc < 4; ++kc) {
        __syncthreads();
        for (int e = tid; e < 792; e += 256) {
            int cell = e >> 2, kcn = e & 3;
            int hr = cell / 66, c = cell - hr * 66;
            int ih = ihb0 - 1 + hr, iw = c - 1;
            s8v v = (s8v)0;
            if ((unsigned)ih < 64u && (unsigned)iw < 64u)
                v = *(const s8v*)(inb + ((size_t)ih * 64 + iw) * 128 + kc * 32 + kcn * 8);
            *(s8v*)&sA[(hr * 66 + c) * 40 + kcn * 8] = v;
        }
        __syncthreads();

#pragma unroll
        for (int a = 0; a < 2; ++a)
#pragma unroll
        for (int b = 0; b < 2; ++b) {
            const int kh = p + 2 * a;
            const int kw = (1 - P) + 2 * b;
            const int tap = kh * 4 + kw;
            const int hrw = mh + 1 - a;
            s8v af[4];
#pragma unroll
            for (int a4 = 0; a4 < 4; ++a4)
                af[a4] = *(const s8v*)&sA[(hrw * 66 + a4 * 16 + rl + P - b + 1) * 40 + qd * 8];
            const short* wbp = wt + (((size_t)(tap * 4 + kc) * 4 + nh * 2) << 9) + l * 8;
#pragma unroll
            for (int nt = 0; nt < 2; ++nt) {
                s8v bb = *(const s8v*)(wbp + ((size_t)nt << 9));
#pragma unroll
                for (int a4 = 0; a4 < 4; ++a4)
                    acc[a4][nt] = mfma16(af[a4], bb, acc[a4][nt]);
            }
        }
    }

#pragma unroll
    for (int a4 = 0; a4 < 4; ++a4) {
#pragma unroll
        for (int rg = 0; rg < 4; ++rg) {
            int j = a4 * 16 + qd * 4 + rg;
            int oh = oh0 + 2 * mh, ow = 2 * j + P;
            size_t pb = (((size_t)n * 128 + oh) * 128 + ow) * 64;
#pragma unroll
            for (int nt = 0; nt < 2; ++nt) {
                int co = nh * 32 + nt * 16 + rl;
                float v = acc[a4][nt][rg] + bias[co];
                out[pb + co] = f2b(fmaxf(v, 0.f));
            }
        }
    }
}

// ---------------------------------------------------------------------------
// ConvT2: in NHWC bf16 (16,128,128,64) -> x_rec fp32 (16,256,256), k4 s2 p1.
// ---------------------------------------------------------------------------
__global__ __launch_bounds__(256)
void convt2_k(const short* __restrict__ in, const float* __restrict__ w,
              const float* __restrict__ bias, float* __restrict__ out)
{
    __shared__ float sw[16 * 64];
    const int tid = threadIdx.x;
    for (int e = tid; e < 1024; e += 256) { int ci = e >> 4, tap = e & 15; sw[tap * 64 + ci] = w[e]; }
    __syncthreads();

    const int i = blockIdx.x * 256 + tid;
    const int n = i >> 16, s = i & 65535;
    const int oh = s >> 8, ow = s & 255;

    const int p = (oh + 1) & 1, q = (ow + 1) & 1;
    const int ihb = (oh + 1 - p) >> 1, iwb = (ow + 1 - q) >> 1;

    float acc = bias[0];
#pragma unroll
    for (int a = 0; a < 2; ++a) {
        int ih = ihb - a, kh = p + 2 * a;
        bool vr = (unsigned)ih < 128u;
#pragma unroll
        for (int b = 0; b < 2; ++b) {
            int iw = iwb - b, kw = q + 2 * b;
            if (vr && (unsigned)iw < 128u) {
                const short* ip = in + (((size_t)n * 128 + ih) * 128 + iw) * 64;
                const float* wp = &sw[(kh * 4 + kw) * 64];
#pragma unroll
                for (int c = 0; c < 64; c += 8) {
                    s8v v = *(const s8v*)(ip + c);
#pragma unroll
                    for (int j = 0; j < 8; ++j) acc += b2f(v[j]) * wp[c + j];
                }
            }
        }
    }
    out[i] = acc;
}

// ---------------------------------------------------------------------------
// VQ: MFMA distance GEMM, split-bf16, fully-coalesced; no global atomics.
// ---------------------------------------------------------------------------
__global__ __launch_bounds__(256)
void vqm_k(const float* __restrict__ z, const short* __restrict__ cbh,
           const short* __restrict__ cbl, const float* __restrict__ cbsq,
           const float* __restrict__ cb,
           float* __restrict__ quant, short* __restrict__ qb,
           int* __restrict__ idxp, float* __restrict__ errbuf)
{
    __shared__ float zs[64 * 68];
    __shared__ short scb[2][8192];
    __shared__ int sidx[64];
    __shared__ float serr[4];
    float* qc = (float*)&scb[0][0];

    const int tid = threadIdx.x;
    const int w = tid >> 6, l = tid & 63, rl = l & 15, qd = l >> 4;
    const int r0 = blockIdx.x * 64;

    for (int e = tid; e < 1024; e += 256) {
        int row = e >> 4, c4 = e & 15;
        float4 t = ((const float4*)(z + (size_t)(r0 + row) * 64))[c4];
        *(float4*)&zs[row * 68 + c4 * 4] = t;
    }
    __syncthreads();

    s8v zh[2], zl[2];
#pragma unroll
    for (int kc = 0; kc < 2; ++kc) {
        const float* zp = &zs[(w * 16 + rl) * 68 + kc * 32 + qd * 8];
        s8v hi, lo;
#pragma unroll
        for (int j = 0; j < 8; ++j) {
            float v = zp[j];
            short h = f2b(v);
            hi[j] = h;
            lo[j] = f2b(v - b2f(h));
        }
        zh[kc] = hi; zl[kc] = lo;
    }

    float best[4]; int bidx[4];
#pragma unroll
    for (int rg = 0; rg < 4; ++rg) { best[rg] = 3.4e38f; bidx[rg] = 0; }

    for (int ch = 0; ch < 4; ++ch) {
        __syncthreads();
        for (int e = tid; e < 1024; e += 256) {
            int kcL = e >> 9, rest = e & 511;
            int ntl = rest >> 6, off = rest & 63;
            int srcIdx = (kcL * 32 + ch * 8 + ntl) * 64 + off;
            *(s8v*)&scb[0][e * 8] = ((const s8v*)cbh)[srcIdx];
            *(s8v*)&scb[1][e * 8] = ((const s8v*)cbl)[srcIdx];
        }
        __syncthreads();

        float sq[8];
#pragma unroll
        for (int nt = 0; nt < 8; ++nt) sq[nt] = cbsq[ch * 128 + nt * 16 + rl];

        f4v acc[8];
#pragma unroll
        for (int nt = 0; nt < 8; ++nt) acc[nt] = (f4v)0.f;
#pragma unroll
        for (int kc = 0; kc < 2; ++kc) {
#pragma unroll
            for (int nt = 0; nt < 8; ++nt) {
                s8v bh = *(const s8v*)&scb[0][(kc * 8 + nt) * 512 + l * 8];
                s8v bl = *(const s8v*)&scb[1][(kc * 8 + nt) * 512 + l * 8];
                acc[nt] = mfma16(zh[kc], bh, acc[nt]);
                acc[nt] = mfma16(zh[kc], bl, acc[nt]);
                acc[nt] = mfma16(zl[kc], bh, acc[nt]);
            }
        }

#pragma unroll
        for (int rg = 0; rg < 4; ++rg) {
            float bd = best[rg]; int bi = bidx[rg];
#pragma unroll
            for (int nt = 0; nt < 8; ++nt) {
                float d = sq[nt] - 2.f * acc[nt][rg];
                int code = ch * 128 + nt * 16 + rl;
                if (d < bd) { bd = d; bi = code; }
            }
            best[rg] = bd; bidx[rg] = bi;
        }
    }

#pragma unroll
    for (int rg = 0; rg < 4; ++rg) {
        float bd = best[rg]; int bi = bidx[rg];
#pragma unroll
        for (int off = 1; off < 16; off <<= 1) {
            float od = __shfl_xor(bd, off, 64);
            int   oi = __shfl_xor(bi, off, 64);
            if (od < bd || (od == bd && oi < bi)) { bd = od; bi = oi; }
        }
        if (rl == 0) sidx[w * 16 + qd * 4 + rg] = bi;
    }
    __syncthreads();

    const int n = r0 >> 12, s0 = r0 & 4095;
    float err = 0.f;
#pragma unroll 4
    for (int i = 0; i < 16; ++i) {
        int rr = w * 16 + i;
        int bi = sidx[rr];
        float c = cb[(size_t)bi * 64 + l];
        float zv = zs[rr * 68 + l];
        float dd = zv - c;
        err += dd * dd;
        qb[(size_t)(r0 + rr) * 64 + l] = f2b(c);
        qc[l * 68 + rr] = c;
    }
#pragma unroll
    for (int o = 32; o; o >>= 1) err += __shfl_down(err, o, 64);
    if (l == 0) serr[w] = err;
    if (tid < 64) idxp[r0 + tid] = sidx[tid];
    __syncthreads();

#pragma unroll 4
    for (int dd = 0; dd < 16; ++dd) {
        int d = w * 16 + dd;
        quant[((size_t)(n * 64 + d)) * 4096 + s0 + l] = qc[d * 68 + l];
    }
    if (tid == 0) errbuf[blockIdx.x] = serr[0] + serr[1] + serr[2] + serr[3];
}

__global__ __launch_bounds__(1024)
void fin_k(const int* __restrict__ idxp, const float* __restrict__ errbuf,
           float* out_loss, float* out_perp)
{
    __shared__ int lc[512];
    __shared__ float red[1024];
    const int t = threadIdx.x;
    if (t < 512) lc[t] = 0;
    __syncthreads();
    for (int i = t; i < 65536; i += 1024) atomicAdd(&lc[idxp[i]], 1);
    __syncthreads();
    float v = 0.f;
    if (t < 512) {
        float avg = (float)lc[t] * (1.0f / 65536.0f);
        v = avg * logf(avg + 1e-10f);
    }
    red[t] = v;
    __syncthreads();
    for (int st = 512; st; st >>= 1) { if (t < st) red[t] += red[t + st]; __syncthreads(); }
    if (t == 0) *out_perp = expf(-red[0]);
    __syncthreads();
    red[t] = errbuf[t];
    __syncthreads();
    for (int st = 512; st; st >>= 1) { if (t < st) red[t] += red[t + st]; __syncthreads(); }
    if (t == 0) *out_loss = red[0] * (1.25f / 4194304.0f);
}

__global__ __launch_bounds__(256)
void enc_k(const int* __restrict__ idxp, float4* __restrict__ enc)
{
    int i = blockIdx.x * 256 + threadIdx.x;
    int r = i >> 7, c4 = (i & 127) * 4;
    int k = idxp[r];
    float4 v;
    v.x = (k == c4)     ? 1.f : 0.f;
    v.y = (k == c4 + 1) ? 1.f : 0.f;
    v.z = (k == c4 + 2) ? 1.f : 0.f;
    v.w = (k == c4 + 3) ? 1.f : 0.f;
    enc[i] = v;
}

// ---------------------------------------------------------------------------
extern "C" void kernel_launch(void* const* d_in, const int* in_sizes, int n_in,
                              void* d_out, int out_size, void* d_ws, size_t ws_size,
                              hipStream_t stream)
{
    const float* x    = (const float*)d_in[0];
    const float* ew1  = (const float*)d_in[1];
    const float* eb1  = (const float*)d_in[2];
    const float* ew2  = (const float*)d_in[3];
    const float* eb2  = (const float*)d_in[4];
    const float* ew3  = (const float*)d_in[5];
    const float* eb3  = (const float*)d_in[6];
    const float* er1a = (const float*)d_in[7];
    const float* er1b = (const float*)d_in[8];
    const float* er2a = (const float*)d_in[9];
    const float* er2b = (const float*)d_in[10];
    const float* pw   = (const float*)d_in[11];
    const float* pb   = (const float*)d_in[12];
    const float* cb   = (const float*)d_in[13];
    const float* dw1w = (const float*)d_in[14];
    const float* db1  = (const float*)d_in[15];
    const float* dr1a = (const float*)d_in[16];
    const float* dr1b = (const float*)d_in[17];
    const float* dr2a = (const float*)d_in[18];
    const float* dr2b = (const float*)d_in[19];
    const float* dtw1 = (const float*)d_in[20];
    const float* dtb1 = (const float*)d_in[21];
    const float* dtw2 = (const float*)d_in[22];
    const float* dtb2 = (const float*)d_in[23];

    char* wsb = (char*)d_ws;
    short* wbase = (short*)wsb;
    short* wt2   = wbase;
    short* wt3   = wbase + 131072;
    short* wr1a  = wbase + 278528;
    short* wr1b  = wbase + 315392;
    short* wr2a  = wbase + 319488;
    short* wr2b  = wbase + 356352;
    short* wpwt  = wbase + 360448;
    short* wd1   = wbase + 368640;
    short* wdr1a = wbase + 442368;
    short* wdr1b = wbase + 479232;
    short* wdr2a = wbase + 483328;
    short* wdr2b = wbase + 520192;
    short* wtt1  = wbase + 524288;

    short* h2   = (short*)(wsb + 1310720);
    short* buf  = (short*)(wsb + 18087936);
    short* qb   = (short*)(wsb + 39059456);
    float* z    = (float*)(wsb + 47448064);
    int*   idx  = (int*)  (wsb + 64225280);
    if (ws_size < (size_t)64489480) return;

    float* out    = (float*)d_out;
    float* o_loss = out;
    float* xrec   = out + 1;
    float* o_perp = out + 1048577;
    float* enc    = out + 1048578;
    float* quant  = out + 34603010;
    char*  encB = (char*)d_out + (size_t)1048580 * 4;
    short* h1  = (short*)encB;
    short* dt1 = h1 + 16777216;
    short* cbh  = (short*)(encB + ((size_t)120 << 20));
    short* cbl  = cbh + 32768;
    float* cbsq = (float*)(cbl + 32768);
    float* errbuf = (float*)(encB + ((size_t)121 << 20));

    WtArgs wa;
    wa.d[0]  = { ew2,  128,  64, 16, 0, 0      };
    wa.d[1]  = { ew3,  128, 128,  9, 0, 131072 };
    wa.d[2]  = { er1a,  32, 128,  9, 0, 278528 };
    wa.d[3]  = { er1b, 128,  32,  1, 0, 315392 };
    wa.d[4]  = { er2a,  32, 128,  9, 0, 319488 };
    wa.d[5]  = { er2b, 128,  32,  1, 0, 356352 };
    wa.d[6]  = { pw,    64, 128,  1, 0, 360448 };
    wa.d[7]  = { dw1w, 128,  64,  9, 0, 368640 };
    wa.d[8]  = { dr1a,  32, 128,  9, 0, 442368 };
    wa.d[9]  = { dr1b, 128,  32,  1, 0, 479232 };
    wa.d[10] = { dr2a,  32, 128,  9, 0, 483328 };
    wa.d[11] = { dr2b, 128,  32,  1, 0, 520192 };
    wa.d[12] = { dtw1,  64, 128, 16, 1, 524288 };
    wa.total = 655360;
    wtall_k<<<dim3(2560), TPB, 0, stream>>>(wa, wbase);
    cbprep_k<<<dim3(2), TPB, 0, stream>>>(cb, cbh, cbl, cbsq);

    // ---- encoder ----
    conv1_k<<<dim3(128, 16), TPB, 0, stream>>>(x, ew1, eb1, h1);
    pconv2_k<<<dim3(64, 16), TPB, 0, stream>>>(h1, wt2, eb2, h2);
    pconv3s_k<128,128,false,false,false><<<dim3(64,16), TPB, 0, stream>>>(h2, wt3, eb3, buf);
    rfuse_k<<<dim3(64,16), TPB, 0, stream>>>(buf, wr1a, wr1b, h2);   // res1: buf -> h2
    rfuse_k<<<dim3(64,16), TPB, 0, stream>>>(h2,  wr2a, wr2b, buf);  // res2: h2 -> buf
    pconv1s_k<128, 64,true ,false,true ><<<dim3(1024), TPB, 0, stream>>>(buf, wpwt, pb, z);

    // ---- VQ ----
    vqm_k<<<dim3(1024), TPB, 0, stream>>>(z, cbh, cbl, cbsq, cb, quant, qb, idx, errbuf);
    fin_k<<<dim3(1), 1024, 0, stream>>>(idx, errbuf, o_loss, o_perp);

    // ---- decoder ----
    pconv3s_k< 64,128,false,false,false><<<dim3(64,16), TPB, 0, stream>>>(qb, wd1, db1, buf);
    rfuse_k<<<dim3(64,16), TPB, 0, stream>>>(buf, wdr1a, wdr1b, h2);  // dres1: buf -> h2
    rfuse_k<<<dim3(64,16), TPB, 0, stream>>>(h2,  wdr2a, wdr2b, buf); // dres2: h2 -> buf
    pct1_k<<<dim3(128, 16), TPB, 0, stream>>>(buf, wtt1, dtb1, dt1);
    convt2_k<<<dim3(4096), TPB, 0, stream>>>(dt1, dtw2, dtb2, xrec);

    // ---- encodings (last) ----
    enc_k<<<dim3(32768), TPB, 0, stream>>>(idx, (float4*)enc);
}